// Round 10
// baseline (890.843 us; speedup 1.0000x reference)
//
#include <hip/hip_runtime.h>

// SpikingMultiHeadAttention — B=2, S=2048, D=1024, H=16, hd=64, fp32 I/O.
// Round 13: r12 base + ONE change: attn_mfma defers the attn-tile NT stores
// by one iteration. __syncthreads drains vmcnt(0) incl. store-acks; stores
// were issued ~200cy before the barrier -> per-iteration HBM-latency stall.
// Now: tile h's mask words (2 VGPR) are saved; its 2 f4 NT stores issue at
// iteration h+1 AFTER the V/stage loads (vmcnt retires in-order, so PV's
// V-load wait doesn't wait on them) and complete under h+1's full compute.
// Tile 63 flushed after the loop. Same values/addresses -> absmax 1.75.
// Bit algebra (verified at lanes 0/17/35/63):
//   ballot cmp[n2][r]: bit l' = P[(l'>>4)*4+r][n2*16+(l'&15)]
//   pa[j]=P[la][qd*8+j]: bit ((la>>2)*16+(qd&1)*8+j) of cmp[qd>>1][la&3]
//   attn row it*8+(lane>>3), col (lane&7)*4+u:
//     bit ((lane>>5)<<4)+(lane&3)*4 + it*32 + u of cmp[(lane>>2)&1][(lane>>3)&3]
// MFMA 16x16x32 bf16 layouts (HW-verified):
//   A-frag: lane holds A[m=lane&15][k=(lane>>4)*8+j], j=0..7
//   B-frag: lane holds Bt[n=lane&15][k=(lane>>4)*8+j]
//   C/D:    lane,reg r -> row m=(lane>>4)*4+r, col n=lane&15

#define SEQ 2048
#define DIM 1024
#define NH 16
#define HD 64
#define BATCH 2
#define MROWS (BATCH * SEQ)   // 4096
#define BHT (BATCH * NH)      // 32

typedef __attribute__((ext_vector_type(8))) short short8;
typedef __attribute__((ext_vector_type(4))) float f4;
typedef unsigned short ushort;
typedef unsigned long long u64;

__device__ __forceinline__ f4 mfma16(short8 a, short8 b, f4 c) {
    return __builtin_amdgcn_mfma_f32_16x16x32_bf16(a, b, c, 0, 0, 0);
}
__device__ __forceinline__ ushort rne16(float x) {
    union { float f; unsigned u; } a; a.f = x;
    return (ushort)((a.u + 0x7fffu + ((a.u >> 16) & 1u)) >> 16);
}
// x ~= hi + lo: hi = truncate-to-bf16(x), lo = rne-bf16(x - hi)
__device__ __forceinline__ void split2(float x, ushort& h, ushort& l) {
    union { float f; unsigned u; } a; a.f = x;
    unsigned hu = a.u & 0xffff0000u;
    h = (ushort)(hu >> 16);
    union { unsigned u; float f; } hb; hb.u = hu;
    l = rne16(x - hb.f);
}
__device__ __forceinline__ short8 ld8(const ushort* p) { return *(const short8*)p; }

// async global->LDS, 16B per lane; LDS dest wave-uniform base, HW writes
// lane i at base + i*16. Global addr is per-lane.
__device__ __forceinline__ void gll16(const ushort* g, ushort* l) {
    __builtin_amdgcn_global_load_lds((const __attribute__((address_space(1))) void*)g,
                                     (__attribute__((address_space(3))) void*)l, 16, 0, 0);
}

// 4-way select of wave-uniform u64 masks by per-lane index r (0..3)
__device__ __forceinline__ u64 sel4(const u64 c0, const u64 c1, const u64 c2, const u64 c3,
                                    int r) {
    u64 m01 = (r & 1) ? c1 : c0;
    u64 m23 = (r & 1) ? c3 : c2;
    return (r & 2) ? m23 : m01;
}

// ---------- fused weight conversion: 4 jobs on grid.y ----------
__global__ __launch_bounds__(256) void wconv(const float* __restrict__ Wq,
                                             const float* __restrict__ Wk,
                                             const float* __restrict__ Wv,
                                             const float* __restrict__ Wo,
                                             ushort* __restrict__ Wqh, ushort* __restrict__ Wql,
                                             ushort* __restrict__ Wkh, ushort* __restrict__ Wkl,
                                             ushort* __restrict__ Wvb, ushort* __restrict__ Wob) {
    int i = (blockIdx.x * 256 + threadIdx.x) * 4;
    int job = blockIdx.y;
    const float* src = job == 0 ? Wq : job == 1 ? Wk : job == 2 ? Wv : Wo;
    float4 w = *(const float4*)&src[i];
    float xs[4] = {w.x, w.y, w.z, w.w};
    if (job < 2) {
        ushort h[4], l[4];
#pragma unroll
        for (int j = 0; j < 4; ++j) split2(xs[j], h[j], l[j]);
        ushort* ph = job ? Wkh : Wqh;
        ushort* pl = job ? Wkl : Wql;
        *(short4*)&ph[i] = make_short4(h[0], h[1], h[2], h[3]);
        *(short4*)&pl[i] = make_short4(l[0], l[1], l[2], l[3]);
    } else {
        ushort* po = job == 2 ? Wvb : Wob;
        *(short4*)&po[i] = make_short4(rne16(xs[0]), rne16(xs[1]), rne16(xs[2]), rne16(xs[3]));
    }
}

// ---------- fused q/k/v projection: W LDS-staged (dbuf, swizzled) ----------
// Grid (32, 16, 3). 4 waves/block share the W tile (same n0, different m0).
// LDS: wst[2][2][64][64] = 32 KiB (+ Ts 20 KiB for z==2) -> 2-3 blocks/CU.
__global__ __launch_bounds__(256, 2) void proj_qkv(
    const float* __restrict__ query, const float* __restrict__ key, const float* __restrict__ value,
    const ushort* __restrict__ Wqh, const ushort* __restrict__ Wql,
    const ushort* __restrict__ Wkh, const ushort* __restrict__ Wkl,
    const ushort* __restrict__ Wvb,
    const float* __restrict__ bq, const float* __restrict__ bk, const float* __restrict__ bv,
    ushort* __restrict__ Qhi, ushort* __restrict__ Qlo,
    ushort* __restrict__ Khi, ushort* __restrict__ Klo, ushort* __restrict__ Vt) {
    __shared__ ushort wst[2][2][64][64];  // [buf][hi/lo][row][hw], chunk-swizzled content
    __shared__ ushort Ts[4][64][40];      // z==2 transpose staging (wave-private rows)
    const int z = blockIdx.z;
    const int t = threadIdx.x, wave = t >> 6, lane = t & 63;
    const int la = lane & 15, qd = lane >> 4;
    const int m0 = blockIdx.x * 128 + wave * 32;
    const int n0 = blockIdx.y * 64;

    // staging geometry: wave w stages rows [w*16, w*16+16) of the 64-row W tile
    // in two 8-row gll16 groups. lane l -> row group+(l>>3), chunk (l&7).
    // LDS slot [row][j] holds GLOBAL chunk j^(row&7) (involution); row&7 == l>>3.
    const int srow = wave * 16 + (lane >> 3);
    const int schunk = (lane & 7) ^ (lane >> 3);
    const size_t wg0 = (size_t)(n0 + srow) * DIM + schunk * 8;

    if (z < 2) {
        const float* X = z ? key : query;
        const ushort* Wh = z ? Wkh : Wqh;
        const ushort* Wl = z ? Wkl : Wql;

        // prologue: stage k0=0 into buf 0
        gll16(&Wh[wg0], &wst[0][0][wave * 16][0]);
        gll16(&Wh[wg0 + 8 * DIM], &wst[0][0][wave * 16 + 8][0]);
        gll16(&Wl[wg0], &wst[0][1][wave * 16][0]);
        gll16(&Wl[wg0 + 8 * DIM], &wst[0][1][wave * 16 + 8][0]);
        __syncthreads();

        f4 acc[2][4] = {};
        for (int k0 = 0; k0 < DIM; k0 += 64) {
            const int cur = (k0 >> 6) & 1;
            // A loads for this k0 (both 32-k halves), fp32 register path
            float4 xA[2][2][2];  // [half][ms][2]
#pragma unroll
            for (int hf = 0; hf < 2; ++hf)
#pragma unroll
                for (int ms = 0; ms < 2; ++ms) {
                    const float* ap = &X[(size_t)(m0 + ms * 16 + la) * DIM + k0 + hf * 32 + qd * 8];
                    xA[hf][ms][0] = *(const float4*)ap;
                    xA[hf][ms][1] = *(const float4*)(ap + 4);
                }
            // async-stage k0+64 into the other buffer
            if (k0 + 64 < DIM) {
                gll16(&Wh[wg0 + k0 + 64], &wst[cur ^ 1][0][wave * 16][0]);
                gll16(&Wh[wg0 + k0 + 64 + 8 * DIM], &wst[cur ^ 1][0][wave * 16 + 8][0]);
                gll16(&Wl[wg0 + k0 + 64], &wst[cur ^ 1][1][wave * 16][0]);
                gll16(&Wl[wg0 + k0 + 64 + 8 * DIM], &wst[cur ^ 1][1][wave * 16 + 8][0]);
            }
#pragma unroll
            for (int hf = 0; hf < 2; ++hf) {
                short8 ahi[2], alo[2];
#pragma unroll
                for (int ms = 0; ms < 2; ++ms) {
                    float xs[8] = {xA[hf][ms][0].x, xA[hf][ms][0].y, xA[hf][ms][0].z,
                                   xA[hf][ms][0].w, xA[hf][ms][1].x, xA[hf][ms][1].y,
                                   xA[hf][ms][1].z, xA[hf][ms][1].w};
#pragma unroll
                    for (int j = 0; j < 8; ++j) {
                        ushort h, l;
                        split2(xs[j], h, l);
                        ahi[ms][j] = (short)h;
                        alo[ms][j] = (short)l;
                    }
                }
#pragma unroll
                for (int ns = 0; ns < 4; ++ns) {
                    int row = ns * 16 + la;
                    int sw = ((hf * 4 + qd) ^ (la & 7)) * 8;
                    short8 wHf = *(const short8*)&wst[cur][0][row][sw];
                    short8 wLf = *(const short8*)&wst[cur][1][row][sw];
#pragma unroll
                    for (int ms = 0; ms < 2; ++ms) {
                        acc[ms][ns] = mfma16(alo[ms], wHf, acc[ms][ns]);
                        acc[ms][ns] = mfma16(ahi[ms], wLf, acc[ms][ns]);
                        acc[ms][ns] = mfma16(ahi[ms], wHf, acc[ms][ns]);
                    }
                }
            }
            __syncthreads();  // release wst[cur]; stage of k0+64 has landed
        }
        const float* bias = z ? bk : bq;
        ushort* Oh = z ? Khi : Qhi;
        ushort* Ol = z ? Klo : Qlo;
#pragma unroll
        for (int ns = 0; ns < 4; ++ns) {
            int n = n0 + ns * 16 + la;
            float bvv = bias[n];
            int h = n >> 6, d = n & 63;
#pragma unroll
            for (int ms = 0; ms < 2; ++ms)
#pragma unroll
                for (int r = 0; r < 4; ++r) {
                    int m = m0 + ms * 16 + qd * 4 + r;
                    int b = m >> 11, s = m & 2047;
                    ushort hh, ll;
                    split2(acc[ms][ns][r] + bvv, hh, ll);
                    size_t o = ((size_t)(b * NH + h) * SEQ + s) * HD + d;
                    __builtin_nontemporal_store(hh, &Oh[o]);
                    __builtin_nontemporal_store(ll, &Ol[o]);
                }
        }
    } else {
        // V projection: single bf16 W, same staging (hl=0 only)
        gll16(&Wvb[wg0], &wst[0][0][wave * 16][0]);
        gll16(&Wvb[wg0 + 8 * DIM], &wst[0][0][wave * 16 + 8][0]);
        __syncthreads();

        f4 acc[2][4] = {};
        for (int k0 = 0; k0 < DIM; k0 += 64) {
            const int cur = (k0 >> 6) & 1;
            float4 xA[2][2][2];
#pragma unroll
            for (int hf = 0; hf < 2; ++hf)
#pragma unroll
                for (int ms = 0; ms < 2; ++ms) {
                    const float* ap =
                        &value[(size_t)(m0 + ms * 16 + la) * DIM + k0 + hf * 32 + qd * 8];
                    xA[hf][ms][0] = *(const float4*)ap;
                    xA[hf][ms][1] = *(const float4*)(ap + 4);
                }
            if (k0 + 64 < DIM) {
                gll16(&Wvb[wg0 + k0 + 64], &wst[cur ^ 1][0][wave * 16][0]);
                gll16(&Wvb[wg0 + k0 + 64 + 8 * DIM], &wst[cur ^ 1][0][wave * 16 + 8][0]);
            }
#pragma unroll
            for (int hf = 0; hf < 2; ++hf) {
                short8 a[2];
#pragma unroll
                for (int ms = 0; ms < 2; ++ms) {
                    float xs[8] = {xA[hf][ms][0].x, xA[hf][ms][0].y, xA[hf][ms][0].z,
                                   xA[hf][ms][0].w, xA[hf][ms][1].x, xA[hf][ms][1].y,
                                   xA[hf][ms][1].z, xA[hf][ms][1].w};
#pragma unroll
                    for (int j = 0; j < 8; ++j) a[ms][j] = (short)rne16(xs[j]);
                }
#pragma unroll
                for (int ns = 0; ns < 4; ++ns) {
                    int row = ns * 16 + la;
                    int sw = ((hf * 4 + qd) ^ (la & 7)) * 8;
                    short8 wv = *(const short8*)&wst[cur][0][row][sw];
#pragma unroll
                    for (int ms = 0; ms < 2; ++ms) acc[ms][ns] = mfma16(a[ms], wv, acc[ms][ns]);
                }
            }
            __syncthreads();
        }
#pragma unroll
        for (int ns = 0; ns < 4; ++ns) {
            float bvv = bv[n0 + ns * 16 + la];
#pragma unroll
            for (int ms = 0; ms < 2; ++ms)
#pragma unroll
                for (int r = 0; r < 4; ++r)
                    Ts[wave][ns * 16 + la][ms * 16 + qd * 4 + r] = rne16(acc[ms][ns][r] + bvv);
        }
        // same-wave LDS round-trip (lgkmcnt-ordered, wave-private region)
        int b = m0 >> 11, s0 = m0 & 2047, h = n0 >> 6;
        size_t vbase = (size_t)(b * NH + h) * HD * SEQ;
#pragma unroll
        for (int it = 0; it < 4; ++it) {
            int d = it * 16 + (lane >> 2), sc = (lane & 3) * 8;
            short8 v0 = *(const short8*)&Ts[wave][d][sc];
            __builtin_nontemporal_store(v0, (short8*)&Vt[vbase + (size_t)d * SEQ + s0 + sc]);
        }
    }
}

// ---------- fused attention: LDS-staged K, ballot P, deferred attn stores ----
// Grid 32 (bh) x 32 (q-blocks of 64). 4 waves/block share the K tile.
// LDS: kb[2][2][32][64] = 16 KiB -> 4 blocks/CU (grid-capped).
__global__ __launch_bounds__(256, 4) void attn_mfma(
    const ushort* __restrict__ Qhi, const ushort* __restrict__ Qlo,
    const ushort* __restrict__ Khi, const ushort* __restrict__ Klo,
    const ushort* __restrict__ Vt, float* __restrict__ attn, ushort* __restrict__ ctxb) {
    __shared__ ushort kb[2][2][32][64];  // [buf][hl][key][halfword], chunk-swizzled content
    const int t = threadIdx.x, wave = t >> 6, lane = t & 63;
    const int la = lane & 15, qd = lane >> 4;
    const int bh = blockIdx.x;
    const int q0 = blockIdx.y * 64 + wave * 16;

    short8 qhi[2], qlo[2];
#pragma unroll
    for (int ks = 0; ks < 2; ++ks) {
        size_t qi = ((size_t)bh * SEQ + q0 + la) * HD + ks * 32 + qd * 8;
        qhi[ks] = ld8(&Qhi[qi]);
        qlo[ks] = ld8(&Qlo[qi]);
    }

    const int skey = wave * 8 + (lane >> 3);
    const int schunk = (lane & 7) ^ (lane >> 3);
    const size_t sgbase = ((size_t)bh * SEQ + skey) * HD + schunk * 8;

    // prologue: stage tile 0 into buf 0
    gll16(&Khi[sgbase], &kb[0][0][wave * 8][0]);
    gll16(&Klo[sgbase], &kb[0][1][wave * 8][0]);
    __syncthreads();

    // deferred-store state (masks for tile h-1) + fixed store address base
    const size_t arow0 = ((size_t)bh * SEQ + q0 + (lane >> 3)) * SEQ + (lane & 7) * 4;
    unsigned dblo = 0, dbhi = 0;

    f4 cacc[4] = {};
    for (int h = 0; h < 64; ++h) {
        const int c0 = h * 32;
        const int cur = h & 1;

        short8 vB[4];
#pragma unroll
        for (int ns = 0; ns < 4; ++ns)
            vB[ns] = ld8(&Vt[((size_t)bh * HD + ns * 16 + la) * SEQ + c0 + qd * 8]);

        if (h + 1 < 64) {
            gll16(&Khi[sgbase + (size_t)(c0 + 32) * HD], &kb[cur ^ 1][0][wave * 8][0]);
            gll16(&Klo[sgbase + (size_t)(c0 + 32) * HD], &kb[cur ^ 1][1][wave * 8][0]);
        }

        // deferred attn stores for tile h-1: issued AFTER this iteration's
        // loads (vmcnt retires in-order -> PV's V-load wait skips them) and
        // covered by this whole iteration's compute before the barrier drain.
        if (h > 0) {
            f4 o0, o1;
            o0.x = (dblo & 1u) ? 1.f : 0.f;
            o0.y = (dblo & 2u) ? 1.f : 0.f;
            o0.z = (dblo & 4u) ? 1.f : 0.f;
            o0.w = (dblo & 8u) ? 1.f : 0.f;
            o1.x = (dbhi & 1u) ? 1.f : 0.f;
            o1.y = (dbhi & 2u) ? 1.f : 0.f;
            o1.z = (dbhi & 4u) ? 1.f : 0.f;
            o1.w = (dbhi & 8u) ? 1.f : 0.f;
            size_t arow = arow0 + (size_t)(c0 - 32);
            __builtin_nontemporal_store(o0, (f4*)&attn[arow]);
            __builtin_nontemporal_store(o1, (f4*)&attn[arow + (size_t)8 * SEQ]);
        }

        short8 kH[2][2], kL[2][2];
#pragma unroll
        for (int n2 = 0; n2 < 2; ++n2)
#pragma unroll
            for (int ks = 0; ks < 2; ++ks) {
                int row = n2 * 16 + la;
                int sw = ((ks * 4 + qd) ^ (la & 7)) * 8;
                kH[n2][ks] = *(const short8*)&kb[cur][0][row][sw];
                kL[n2][ks] = *(const short8*)&kb[cur][1][row][sw];
            }

        f4 s[2] = {};
        __builtin_amdgcn_s_setprio(1);
#pragma unroll
        for (int n2 = 0; n2 < 2; ++n2)
#pragma unroll
            for (int ks = 0; ks < 2; ++ks) {
                s[n2] = mfma16(qlo[ks], kH[n2][ks], s[n2]);
                s[n2] = mfma16(qhi[ks], kL[n2][ks], s[n2]);
                s[n2] = mfma16(qhi[ks], kH[n2][ks], s[n2]);
            }
        __builtin_amdgcn_s_setprio(0);

        // P tile as 8 wave-uniform 64-bit masks: bit l' of cmpX[r] =
        // P[(l'>>4)*4+r][n2*16+(l'&15)]
        u64 c00 = __ballot(s[0][0] > 0.f), c01 = __ballot(s[0][1] > 0.f);
        u64 c02 = __ballot(s[0][2] > 0.f), c03 = __ballot(s[0][3] > 0.f);
        u64 c10 = __ballot(s[1][0] > 0.f), c11 = __ballot(s[1][1] > 0.f);
        u64 c12 = __ballot(s[1][2] > 0.f), c13 = __ballot(s[1][3] > 0.f);

        // pa[j] = P[la][qd*8+j] as bf16 0x3f80/0 (bit-identical to old Ps path)
        u64 mq0 = sel4(c00, c01, c02, c03, lane & 3);
        u64 mq1 = sel4(c10, c11, c12, c13, lane & 3);
        u64 mq = (qd & 2) ? mq1 : mq0;
        unsigned pbits = (unsigned)(mq >> ((la >> 2) * 16 + (qd & 1) * 8)) & 0xffu;
        union { unsigned w[4]; short8 s8; } pau;
#pragma unroll
        for (int w = 0; w < 4; ++w)
            pau.w[w] = ((pbits >> (2 * w)) & 1u ? 0x3f80u : 0u) |
                       ((pbits >> (2 * w + 1)) & 1u ? 0x3f800000u : 0u);
        short8 pa = pau.s8;

        // save this tile's store mask words for next-iteration issue
        {
            int ra = (lane >> 3) & 3;
            u64 ms0 = sel4(c00, c01, c02, c03, ra);
            u64 ms1 = sel4(c10, c11, c12, c13, ra);
            u64 msel = (lane & 4) ? ms1 : ms0;
            u64 msh = msel >> (((lane >> 5) << 4) + (lane & 3) * 4);
            dblo = (unsigned)msh;
            dbhi = (unsigned)(msh >> 32);
        }

        // ctx += P @ V over this 32-key tile
        __builtin_amdgcn_s_setprio(1);
#pragma unroll
        for (int ns = 0; ns < 4; ++ns) cacc[ns] = mfma16(pa, vB[ns], cacc[ns]);
        __builtin_amdgcn_s_setprio(0);

        __syncthreads();
    }
    // flush deferred stores for tile 63
    {
        f4 o0, o1;
        o0.x = (dblo & 1u) ? 1.f : 0.f;
        o0.y = (dblo & 2u) ? 1.f : 0.f;
        o0.z = (dblo & 4u) ? 1.f : 0.f;
        o0.w = (dblo & 8u) ? 1.f : 0.f;
        o1.x = (dbhi & 1u) ? 1.f : 0.f;
        o1.y = (dbhi & 2u) ? 1.f : 0.f;
        o1.z = (dbhi & 4u) ? 1.f : 0.f;
        o1.w = (dbhi & 8u) ? 1.f : 0.f;
        size_t arow = arow0 + (size_t)(63 * 32);
        __builtin_nontemporal_store(o0, (f4*)&attn[arow]);
        __builtin_nontemporal_store(o1, (f4*)&attn[arow + (size_t)8 * SEQ]);
    }
#pragma unroll
    for (int ns = 0; ns < 4; ++ns)
#pragma unroll
        for (int r = 0; r < 4; ++r) {
            int qrow = q0 + qd * 4 + r;
            __builtin_nontemporal_store(rne16(cacc[ns][r]),
                                        &ctxb[((size_t)bh * SEQ + qrow) * HD + ns * 16 + la]);
        }
}

// ---------- out projection: W LDS-staged (dbuf, swizzled) ----------
// Grid (32, 16). 4 waves/block share the W tile (same n0).
// LDS: wst[2][64][64] = 16 KiB -> well within 2 blocks/CU budget.
__global__ __launch_bounds__(256, 2) void proj_out(const ushort* __restrict__ Ctx,
                                                   const ushort* __restrict__ Wb,
                                                   const float* __restrict__ bias,
                                                   float* __restrict__ out) {
    __shared__ ushort wst[2][64][64];  // [buf][row][hw], chunk-swizzled content
    const int t = threadIdx.x, wave = t >> 6, lane = t & 63;
    const int la = lane & 15, qd = lane >> 4;
    const int m0 = blockIdx.x * 128 + wave * 32;
    const int n0 = blockIdx.y * 64;

    const int srow = wave * 16 + (lane >> 3);
    const int schunk = (lane & 7) ^ (lane >> 3);
    const size_t wg0 = (size_t)(n0 + srow) * DIM + schunk * 8;

    // prologue: stage k0=0 into buf 0
    gll16(&Wb[wg0], &wst[0][wave * 16][0]);
    gll16(&Wb[wg0 + 8 * DIM], &wst[0][wave * 16 + 8][0]);
    __syncthreads();

    f4 acc[2][4] = {};
    for (int k0 = 0; k0 < DIM; k0 += 64) {
        const int cur = (k0 >> 6) & 1;
        const int hsel = k0 >> 6;  // head index = k/64 (constant within the tile)
        // Ctx loads (per-wave rows, register path)
        short8 aO[2][2];  // [half][ms]
#pragma unroll
        for (int hf = 0; hf < 2; ++hf)
#pragma unroll
            for (int ms = 0; ms < 2; ++ms) {
                int m = m0 + ms * 16 + la;
                int b = m >> 11, s = m & 2047;
                aO[hf][ms] =
                    ld8(&Ctx[((size_t)(b * NH + hsel) * SEQ + s) * HD + hf * 32 + qd * 8]);
            }
        // async-stage k0+64 into the other buffer
        if (k0 + 64 < DIM) {
            gll16(&Wb[wg0 + k0 + 64], &wst[cur ^ 1][wave * 16][0]);
            gll16(&Wb[wg0 + k0 + 64 + 8 * DIM], &wst[cur ^ 1][wave * 16 + 8][0]);
        }
#pragma unroll
        for (int hf = 0; hf < 2; ++hf)
#pragma unroll
            for (int ns = 0; ns < 4; ++ns) {
                int row = ns * 16 + la;
                int sw = ((hf * 4 + qd) ^ (la & 7)) * 8;
                short8 wv = *(const short8*)&wst[cur][row][sw];
#pragma unroll
                for (int ms = 0; ms < 2; ++ms) acc[ms][ns] = mfma16(aO[hf][ms], wv, acc[ms][ns]);
            }
        __syncthreads();  // release wst[cur]; stage of k0+64 has landed
    }
#pragma unroll
    for (int ns = 0; ns < 4; ++ns) {
        int n = n0 + ns * 16 + la;
        float bvv = bias[n];
#pragma unroll
        for (int ms = 0; ms < 2; ++ms)
#pragma unroll
            for (int r = 0; r < 4; ++r) {
                int m = m0 + ms * 16 + qd * 4 + r;
                __builtin_nontemporal_store(acc[ms][ns][r] + bvv, &out[(size_t)m * DIM + n]);
            }
    }
}

extern "C" void kernel_launch(void* const* d_in, const int* in_sizes, int n_in,
                              void* d_out, int out_size, void* d_ws, size_t ws_size,
                              hipStream_t stream) {
    const float* query = (const float*)d_in[0];
    const float* key   = (const float*)d_in[1];
    const float* value = (const float*)d_in[2];
    const float* Wq = (const float*)d_in[3];
    const float* bq = (const float*)d_in[4];
    const float* Wk = (const float*)d_in[5];
    const float* bk = (const float*)d_in[6];
    const float* Wv = (const float*)d_in[7];
    const float* bv = (const float*)d_in[8];
    const float* Wo = (const float*)d_in[9];
    const float* bo = (const float*)d_in[10];

    float* out  = (float*)d_out;
    float* attn = out + (size_t)MROWS * DIM;

    const size_t NE = (size_t)MROWS * DIM;  // 4,194,304
    const size_t WE = (size_t)DIM * DIM;    // 1,048,576
    ushort* Qhi = (ushort*)d_ws;            // 5 x NE = 40 MiB
    ushort* Qlo = Qhi + NE;
    ushort* Khi = Qlo + NE;
    ushort* Klo = Khi + NE;
    ushort* Vt  = Klo + NE;
    ushort* Wqh = Vt + NE;                  // 6 x WE = 12 MiB
    ushort* Wql = Wqh + WE;
    ushort* Wkh = Wql + WE;
    ushort* Wkl = Wkh + WE;
    ushort* Wvb = Wkl + WE;
    ushort* Wob = Wvb + WE;
    ushort* Ctx = Wqh;                      // overlays Wqh..Wkl (dead after proj_qkv)

    dim3 blk(256);
    hipLaunchKernelGGL(wconv, dim3(WE / 1024, 4), blk, 0, stream,
                       Wq, Wk, Wv, Wo, Wqh, Wql, Wkh, Wkl, Wvb, Wob);
    hipLaunchKernelGGL(proj_qkv, dim3(32, 16, 3), blk, 0, stream,
                       query, key, value, Wqh, Wql, Wkh, Wkl, Wvb, bq, bk, bv,
                       Qhi, Qlo, Khi, Klo, Vt);
    hipLaunchKernelGGL(attn_mfma, dim3(32, 32), blk, 0, stream,
                       Qhi, Qlo, Khi, Klo, Vt, attn, Ctx);
    hipLaunchKernelGGL(proj_out, dim3(32, 16), blk, 0, stream, Ctx, Wob, bo, out);
}

// Round 11
// 881.278 us; speedup vs baseline: 1.0109x; 1.0109x over previous
//
#include <hip/hip_runtime.h>

// SpikingMultiHeadAttention — B=2, S=2048, D=1024, H=16, hd=64, fp32 I/O.
// Round 14: r12 base (ballot attn, no deferred stores) + ONE change:
// proj_qkv occupancy 2->4 blocks/CU. Ts (z==2 epilogue transpose buffer) is
// OVERLAYED onto wst (dead after the K-loop; loop-end __syncthreads orders
// the last wst reads before Ts writes; Ts rows wave-private, lgkm-ordered).
// LDS 52->32 KiB, launch_bounds(256,4) -> 16 waves/CU (was 8).
// Numerics bit-identical (same ops, same order): absmax must stay 1.75.
// Bit algebra (verified at lanes 0/17/35/63):
//   ballot cmp[n2][r]: bit l' = P[(l'>>4)*4+r][n2*16+(l'&15)]
//   pa[j]=P[la][qd*8+j]: bit ((la>>2)*16+(qd&1)*8+j) of cmp[qd>>1][la&3]
//   attn row it*8+(lane>>3), col (lane&7)*4+u:
//     bit ((lane>>5)<<4)+(lane&3)*4 + it*32 + u of cmp[(lane>>2)&1][(lane>>3)&3]
// MFMA 16x16x32 bf16 layouts (HW-verified):
//   A-frag: lane holds A[m=lane&15][k=(lane>>4)*8+j], j=0..7
//   B-frag: lane holds Bt[n=lane&15][k=(lane>>4)*8+j]
//   C/D:    lane,reg r -> row m=(lane>>4)*4+r, col n=lane&15

#define SEQ 2048
#define DIM 1024
#define NH 16
#define HD 64
#define BATCH 2
#define MROWS (BATCH * SEQ)   // 4096
#define BHT (BATCH * NH)      // 32

typedef __attribute__((ext_vector_type(8))) short short8;
typedef __attribute__((ext_vector_type(4))) float f4;
typedef unsigned short ushort;
typedef unsigned long long u64;

__device__ __forceinline__ f4 mfma16(short8 a, short8 b, f4 c) {
    return __builtin_amdgcn_mfma_f32_16x16x32_bf16(a, b, c, 0, 0, 0);
}
__device__ __forceinline__ ushort rne16(float x) {
    union { float f; unsigned u; } a; a.f = x;
    return (ushort)((a.u + 0x7fffu + ((a.u >> 16) & 1u)) >> 16);
}
// x ~= hi + lo: hi = truncate-to-bf16(x), lo = rne-bf16(x - hi)
__device__ __forceinline__ void split2(float x, ushort& h, ushort& l) {
    union { float f; unsigned u; } a; a.f = x;
    unsigned hu = a.u & 0xffff0000u;
    h = (ushort)(hu >> 16);
    union { unsigned u; float f; } hb; hb.u = hu;
    l = rne16(x - hb.f);
}
__device__ __forceinline__ short8 ld8(const ushort* p) { return *(const short8*)p; }

// async global->LDS, 16B per lane; LDS dest wave-uniform base, HW writes
// lane i at base + i*16. Global addr is per-lane.
__device__ __forceinline__ void gll16(const ushort* g, ushort* l) {
    __builtin_amdgcn_global_load_lds((const __attribute__((address_space(1))) void*)g,
                                     (__attribute__((address_space(3))) void*)l, 16, 0, 0);
}

// 4-way select of wave-uniform u64 masks by per-lane index r (0..3)
__device__ __forceinline__ u64 sel4(const u64 c0, const u64 c1, const u64 c2, const u64 c3,
                                    int r) {
    u64 m01 = (r & 1) ? c1 : c0;
    u64 m23 = (r & 1) ? c3 : c2;
    return (r & 2) ? m23 : m01;
}

// ---------- fused weight conversion: 4 jobs on grid.y ----------
__global__ __launch_bounds__(256) void wconv(const float* __restrict__ Wq,
                                             const float* __restrict__ Wk,
                                             const float* __restrict__ Wv,
                                             const float* __restrict__ Wo,
                                             ushort* __restrict__ Wqh, ushort* __restrict__ Wql,
                                             ushort* __restrict__ Wkh, ushort* __restrict__ Wkl,
                                             ushort* __restrict__ Wvb, ushort* __restrict__ Wob) {
    int i = (blockIdx.x * 256 + threadIdx.x) * 4;
    int job = blockIdx.y;
    const float* src = job == 0 ? Wq : job == 1 ? Wk : job == 2 ? Wv : Wo;
    float4 w = *(const float4*)&src[i];
    float xs[4] = {w.x, w.y, w.z, w.w};
    if (job < 2) {
        ushort h[4], l[4];
#pragma unroll
        for (int j = 0; j < 4; ++j) split2(xs[j], h[j], l[j]);
        ushort* ph = job ? Wkh : Wqh;
        ushort* pl = job ? Wkl : Wql;
        *(short4*)&ph[i] = make_short4(h[0], h[1], h[2], h[3]);
        *(short4*)&pl[i] = make_short4(l[0], l[1], l[2], l[3]);
    } else {
        ushort* po = job == 2 ? Wvb : Wob;
        *(short4*)&po[i] = make_short4(rne16(xs[0]), rne16(xs[1]), rne16(xs[2]), rne16(xs[3]));
    }
}

// ---------- fused q/k/v projection: W LDS-staged (dbuf, swizzled) ----------
// Grid (32, 16, 3). 4 waves/block share the W tile (same n0, different m0).
// LDS: wst[2][2][64][64] = 32 KiB; Ts overlays wst (epilogue-only).
// launch_bounds(256,4) -> 4 blocks/CU, 16 waves/CU.
__global__ __launch_bounds__(256, 4) void proj_qkv(
    const float* __restrict__ query, const float* __restrict__ key, const float* __restrict__ value,
    const ushort* __restrict__ Wqh, const ushort* __restrict__ Wql,
    const ushort* __restrict__ Wkh, const ushort* __restrict__ Wkl,
    const ushort* __restrict__ Wvb,
    const float* __restrict__ bq, const float* __restrict__ bk, const float* __restrict__ bv,
    ushort* __restrict__ Qhi, ushort* __restrict__ Qlo,
    ushort* __restrict__ Khi, ushort* __restrict__ Klo, ushort* __restrict__ Vt) {
    __shared__ ushort wst[2][2][64][64];  // [buf][hi/lo][row][hw], chunk-swizzled content
    // Ts (z==2 epilogue transpose, [4][64][40] = 20 KiB) overlays wst (32 KiB):
    // wst is dead after the K-loop's final __syncthreads.
    ushort (*Ts)[64][40] = (ushort(*)[64][40])(&wst[0][0][0][0]);
    const int z = blockIdx.z;
    const int t = threadIdx.x, wave = t >> 6, lane = t & 63;
    const int la = lane & 15, qd = lane >> 4;
    const int m0 = blockIdx.x * 128 + wave * 32;
    const int n0 = blockIdx.y * 64;

    // staging geometry: wave w stages rows [w*16, w*16+16) of the 64-row W tile
    // in two 8-row gll16 groups. lane l -> row group+(l>>3), chunk (l&7).
    // LDS slot [row][j] holds GLOBAL chunk j^(row&7) (involution); row&7 == l>>3.
    const int srow = wave * 16 + (lane >> 3);
    const int schunk = (lane & 7) ^ (lane >> 3);
    const size_t wg0 = (size_t)(n0 + srow) * DIM + schunk * 8;

    if (z < 2) {
        const float* X = z ? key : query;
        const ushort* Wh = z ? Wkh : Wqh;
        const ushort* Wl = z ? Wkl : Wql;

        // prologue: stage k0=0 into buf 0
        gll16(&Wh[wg0], &wst[0][0][wave * 16][0]);
        gll16(&Wh[wg0 + 8 * DIM], &wst[0][0][wave * 16 + 8][0]);
        gll16(&Wl[wg0], &wst[0][1][wave * 16][0]);
        gll16(&Wl[wg0 + 8 * DIM], &wst[0][1][wave * 16 + 8][0]);
        __syncthreads();

        f4 acc[2][4] = {};
        for (int k0 = 0; k0 < DIM; k0 += 64) {
            const int cur = (k0 >> 6) & 1;
            // A loads for this k0 (both 32-k halves), fp32 register path
            float4 xA[2][2][2];  // [half][ms][2]
#pragma unroll
            for (int hf = 0; hf < 2; ++hf)
#pragma unroll
                for (int ms = 0; ms < 2; ++ms) {
                    const float* ap = &X[(size_t)(m0 + ms * 16 + la) * DIM + k0 + hf * 32 + qd * 8];
                    xA[hf][ms][0] = *(const float4*)ap;
                    xA[hf][ms][1] = *(const float4*)(ap + 4);
                }
            // async-stage k0+64 into the other buffer
            if (k0 + 64 < DIM) {
                gll16(&Wh[wg0 + k0 + 64], &wst[cur ^ 1][0][wave * 16][0]);
                gll16(&Wh[wg0 + k0 + 64 + 8 * DIM], &wst[cur ^ 1][0][wave * 16 + 8][0]);
                gll16(&Wl[wg0 + k0 + 64], &wst[cur ^ 1][1][wave * 16][0]);
                gll16(&Wl[wg0 + k0 + 64 + 8 * DIM], &wst[cur ^ 1][1][wave * 16 + 8][0]);
            }
#pragma unroll
            for (int hf = 0; hf < 2; ++hf) {
                short8 ahi[2], alo[2];
#pragma unroll
                for (int ms = 0; ms < 2; ++ms) {
                    float xs[8] = {xA[hf][ms][0].x, xA[hf][ms][0].y, xA[hf][ms][0].z,
                                   xA[hf][ms][0].w, xA[hf][ms][1].x, xA[hf][ms][1].y,
                                   xA[hf][ms][1].z, xA[hf][ms][1].w};
#pragma unroll
                    for (int j = 0; j < 8; ++j) {
                        ushort h, l;
                        split2(xs[j], h, l);
                        ahi[ms][j] = (short)h;
                        alo[ms][j] = (short)l;
                    }
                }
#pragma unroll
                for (int ns = 0; ns < 4; ++ns) {
                    int row = ns * 16 + la;
                    int sw = ((hf * 4 + qd) ^ (la & 7)) * 8;
                    short8 wHf = *(const short8*)&wst[cur][0][row][sw];
                    short8 wLf = *(const short8*)&wst[cur][1][row][sw];
#pragma unroll
                    for (int ms = 0; ms < 2; ++ms) {
                        acc[ms][ns] = mfma16(alo[ms], wHf, acc[ms][ns]);
                        acc[ms][ns] = mfma16(ahi[ms], wLf, acc[ms][ns]);
                        acc[ms][ns] = mfma16(ahi[ms], wHf, acc[ms][ns]);
                    }
                }
            }
            __syncthreads();  // release wst[cur]; stage of k0+64 has landed
        }
        const float* bias = z ? bk : bq;
        ushort* Oh = z ? Khi : Qhi;
        ushort* Ol = z ? Klo : Qlo;
#pragma unroll
        for (int ns = 0; ns < 4; ++ns) {
            int n = n0 + ns * 16 + la;
            float bvv = bias[n];
            int h = n >> 6, d = n & 63;
#pragma unroll
            for (int ms = 0; ms < 2; ++ms)
#pragma unroll
                for (int r = 0; r < 4; ++r) {
                    int m = m0 + ms * 16 + qd * 4 + r;
                    int b = m >> 11, s = m & 2047;
                    ushort hh, ll;
                    split2(acc[ms][ns][r] + bvv, hh, ll);
                    size_t o = ((size_t)(b * NH + h) * SEQ + s) * HD + d;
                    __builtin_nontemporal_store(hh, &Oh[o]);
                    __builtin_nontemporal_store(ll, &Ol[o]);
                }
        }
    } else {
        // V projection: single bf16 W, same staging (hl=0 only)
        gll16(&Wvb[wg0], &wst[0][0][wave * 16][0]);
        gll16(&Wvb[wg0 + 8 * DIM], &wst[0][0][wave * 16 + 8][0]);
        __syncthreads();

        f4 acc[2][4] = {};
        for (int k0 = 0; k0 < DIM; k0 += 64) {
            const int cur = (k0 >> 6) & 1;
            float4 xA[2][2][2];
#pragma unroll
            for (int hf = 0; hf < 2; ++hf)
#pragma unroll
                for (int ms = 0; ms < 2; ++ms) {
                    const float* ap =
                        &value[(size_t)(m0 + ms * 16 + la) * DIM + k0 + hf * 32 + qd * 8];
                    xA[hf][ms][0] = *(const float4*)ap;
                    xA[hf][ms][1] = *(const float4*)(ap + 4);
                }
            if (k0 + 64 < DIM) {
                gll16(&Wvb[wg0 + k0 + 64], &wst[cur ^ 1][0][wave * 16][0]);
                gll16(&Wvb[wg0 + k0 + 64 + 8 * DIM], &wst[cur ^ 1][0][wave * 16 + 8][0]);
            }
#pragma unroll
            for (int hf = 0; hf < 2; ++hf) {
                short8 a[2];
#pragma unroll
                for (int ms = 0; ms < 2; ++ms) {
                    float xs[8] = {xA[hf][ms][0].x, xA[hf][ms][0].y, xA[hf][ms][0].z,
                                   xA[hf][ms][0].w, xA[hf][ms][1].x, xA[hf][ms][1].y,
                                   xA[hf][ms][1].z, xA[hf][ms][1].w};
#pragma unroll
                    for (int j = 0; j < 8; ++j) a[ms][j] = (short)rne16(xs[j]);
                }
#pragma unroll
                for (int ns = 0; ns < 4; ++ns) {
                    int row = ns * 16 + la;
                    int sw = ((hf * 4 + qd) ^ (la & 7)) * 8;
                    short8 wv = *(const short8*)&wst[cur][0][row][sw];
#pragma unroll
                    for (int ms = 0; ms < 2; ++ms) acc[ms][ns] = mfma16(a[ms], wv, acc[ms][ns]);
                }
            }
            __syncthreads();
        }
        // epilogue: Ts overlays wst — safe, wst dead after the barrier above
#pragma unroll
        for (int ns = 0; ns < 4; ++ns) {
            float bvv = bv[n0 + ns * 16 + la];
#pragma unroll
            for (int ms = 0; ms < 2; ++ms)
#pragma unroll
                for (int r = 0; r < 4; ++r)
                    Ts[wave][ns * 16 + la][ms * 16 + qd * 4 + r] = rne16(acc[ms][ns][r] + bvv);
        }
        // same-wave LDS round-trip (lgkmcnt-ordered, wave-private region)
        int b = m0 >> 11, s0 = m0 & 2047, h = n0 >> 6;
        size_t vbase = (size_t)(b * NH + h) * HD * SEQ;
#pragma unroll
        for (int it = 0; it < 4; ++it) {
            int d = it * 16 + (lane >> 2), sc = (lane & 3) * 8;
            short8 v0 = *(const short8*)&Ts[wave][d][sc];
            __builtin_nontemporal_store(v0, (short8*)&Vt[vbase + (size_t)d * SEQ + s0 + sc]);
        }
    }
}

// ---------- fused attention: LDS-staged K, ballot-based P (no Ps LDS) ----
// Grid 32 (bh) x 32 (q-blocks of 64). 4 waves/block share the K tile.
// LDS: kb[2][2][32][64] = 16 KiB -> 4 blocks/CU (grid-capped).
__global__ __launch_bounds__(256, 4) void attn_mfma(
    const ushort* __restrict__ Qhi, const ushort* __restrict__ Qlo,
    const ushort* __restrict__ Khi, const ushort* __restrict__ Klo,
    const ushort* __restrict__ Vt, float* __restrict__ attn, ushort* __restrict__ ctxb) {
    __shared__ ushort kb[2][2][32][64];  // [buf][hl][key][halfword], chunk-swizzled content
    const int t = threadIdx.x, wave = t >> 6, lane = t & 63;
    const int la = lane & 15, qd = lane >> 4;
    const int bh = blockIdx.x;
    const int q0 = blockIdx.y * 64 + wave * 16;

    short8 qhi[2], qlo[2];
#pragma unroll
    for (int ks = 0; ks < 2; ++ks) {
        size_t qi = ((size_t)bh * SEQ + q0 + la) * HD + ks * 32 + qd * 8;
        qhi[ks] = ld8(&Qhi[qi]);
        qlo[ks] = ld8(&Qlo[qi]);
    }

    const int skey = wave * 8 + (lane >> 3);
    const int schunk = (lane & 7) ^ (lane >> 3);
    const size_t sgbase = ((size_t)bh * SEQ + skey) * HD + schunk * 8;

    // prologue: stage tile 0 into buf 0
    gll16(&Khi[sgbase], &kb[0][0][wave * 8][0]);
    gll16(&Klo[sgbase], &kb[0][1][wave * 8][0]);
    __syncthreads();

    f4 cacc[4] = {};
    for (int h = 0; h < 64; ++h) {
        const int c0 = h * 32;
        const int cur = h & 1;

        short8 vB[4];
#pragma unroll
        for (int ns = 0; ns < 4; ++ns)
            vB[ns] = ld8(&Vt[((size_t)bh * HD + ns * 16 + la) * SEQ + c0 + qd * 8]);

        if (h + 1 < 64) {
            gll16(&Khi[sgbase + (size_t)(c0 + 32) * HD], &kb[cur ^ 1][0][wave * 8][0]);
            gll16(&Klo[sgbase + (size_t)(c0 + 32) * HD], &kb[cur ^ 1][1][wave * 8][0]);
        }

        short8 kH[2][2], kL[2][2];
#pragma unroll
        for (int n2 = 0; n2 < 2; ++n2)
#pragma unroll
            for (int ks = 0; ks < 2; ++ks) {
                int row = n2 * 16 + la;
                int sw = ((ks * 4 + qd) ^ (la & 7)) * 8;
                kH[n2][ks] = *(const short8*)&kb[cur][0][row][sw];
                kL[n2][ks] = *(const short8*)&kb[cur][1][row][sw];
            }

        f4 s[2] = {};
        __builtin_amdgcn_s_setprio(1);
#pragma unroll
        for (int n2 = 0; n2 < 2; ++n2)
#pragma unroll
            for (int ks = 0; ks < 2; ++ks) {
                s[n2] = mfma16(qlo[ks], kH[n2][ks], s[n2]);
                s[n2] = mfma16(qhi[ks], kL[n2][ks], s[n2]);
                s[n2] = mfma16(qhi[ks], kH[n2][ks], s[n2]);
            }
        __builtin_amdgcn_s_setprio(0);

        // P tile as 8 wave-uniform 64-bit masks: bit l' of cmpX[r] =
        // P[(l'>>4)*4+r][n2*16+(l'&15)]
        u64 c00 = __ballot(s[0][0] > 0.f), c01 = __ballot(s[0][1] > 0.f);
        u64 c02 = __ballot(s[0][2] > 0.f), c03 = __ballot(s[0][3] > 0.f);
        u64 c10 = __ballot(s[1][0] > 0.f), c11 = __ballot(s[1][1] > 0.f);
        u64 c12 = __ballot(s[1][2] > 0.f), c13 = __ballot(s[1][3] > 0.f);

        // pa[j] = P[la][qd*8+j] as bf16 0x3f80/0 (bit-identical to old Ps path)
        u64 mq0 = sel4(c00, c01, c02, c03, lane & 3);
        u64 mq1 = sel4(c10, c11, c12, c13, lane & 3);
        u64 mq = (qd & 2) ? mq1 : mq0;
        unsigned pbits = (unsigned)(mq >> ((la >> 2) * 16 + (qd & 1) * 8)) & 0xffu;
        union { unsigned w[4]; short8 s8; } pau;
#pragma unroll
        for (int w = 0; w < 4; ++w)
            pau.w[w] = ((pbits >> (2 * w)) & 1u ? 0x3f80u : 0u) |
                       ((pbits >> (2 * w + 1)) & 1u ? 0x3f800000u : 0u);
        short8 pa = pau.s8;

        // attn tile straight from masks: lane stores rows it*8+(lane>>3),
        // cols c0+(lane&7)*4+u (same addresses as the old Ps-readback path)
        int ra = (lane >> 3) & 3;
        u64 ms0 = sel4(c00, c01, c02, c03, ra);
        u64 ms1 = sel4(c10, c11, c12, c13, ra);
        u64 msel = (lane & 4) ? ms1 : ms0;
        u64 msh = msel >> (((lane >> 5) << 4) + (lane & 3) * 4);
        unsigned blo = (unsigned)msh, bhi = (unsigned)(msh >> 32);
        f4 o0, o1;
        o0.x = (blo & 1u) ? 1.f : 0.f;
        o0.y = (blo & 2u) ? 1.f : 0.f;
        o0.z = (blo & 4u) ? 1.f : 0.f;
        o0.w = (blo & 8u) ? 1.f : 0.f;
        o1.x = (bhi & 1u) ? 1.f : 0.f;
        o1.y = (bhi & 2u) ? 1.f : 0.f;
        o1.z = (bhi & 4u) ? 1.f : 0.f;
        o1.w = (bhi & 8u) ? 1.f : 0.f;
        {
            size_t arow = ((size_t)bh * SEQ + q0 + (lane >> 3)) * SEQ + c0 + (lane & 7) * 4;
            __builtin_nontemporal_store(o0, (f4*)&attn[arow]);
            __builtin_nontemporal_store(o1, (f4*)&attn[arow + (size_t)8 * SEQ]);
        }

        // ctx += P @ V over this 32-key tile
        __builtin_amdgcn_s_setprio(1);
#pragma unroll
        for (int ns = 0; ns < 4; ++ns) cacc[ns] = mfma16(pa, vB[ns], cacc[ns]);
        __builtin_amdgcn_s_setprio(0);

        __syncthreads();
    }
#pragma unroll
    for (int ns = 0; ns < 4; ++ns)
#pragma unroll
        for (int r = 0; r < 4; ++r) {
            int qrow = q0 + qd * 4 + r;
            __builtin_nontemporal_store(rne16(cacc[ns][r]),
                                        &ctxb[((size_t)bh * SEQ + qrow) * HD + ns * 16 + la]);
        }
}

// ---------- out projection: W LDS-staged (dbuf, swizzled) ----------
// Grid (32, 16). 4 waves/block share the W tile (same n0).
// LDS: wst[2][64][64] = 16 KiB -> well within 2 blocks/CU budget.
__global__ __launch_bounds__(256, 2) void proj_out(const ushort* __restrict__ Ctx,
                                                   const ushort* __restrict__ Wb,
                                                   const float* __restrict__ bias,
                                                   float* __restrict__ out) {
    __shared__ ushort wst[2][64][64];  // [buf][row][hw], chunk-swizzled content
    const int t = threadIdx.x, wave = t >> 6, lane = t & 63;
    const int la = lane & 15, qd = lane >> 4;
    const int m0 = blockIdx.x * 128 + wave * 32;
    const int n0 = blockIdx.y * 64;

    const int srow = wave * 16 + (lane >> 3);
    const int schunk = (lane & 7) ^ (lane >> 3);
    const size_t wg0 = (size_t)(n0 + srow) * DIM + schunk * 8;

    // prologue: stage k0=0 into buf 0
    gll16(&Wb[wg0], &wst[0][wave * 16][0]);
    gll16(&Wb[wg0 + 8 * DIM], &wst[0][wave * 16 + 8][0]);
    __syncthreads();

    f4 acc[2][4] = {};
    for (int k0 = 0; k0 < DIM; k0 += 64) {
        const int cur = (k0 >> 6) & 1;
        const int hsel = k0 >> 6;  // head index = k/64 (constant within the tile)
        // Ctx loads (per-wave rows, register path)
        short8 aO[2][2];  // [half][ms]
#pragma unroll
        for (int hf = 0; hf < 2; ++hf)
#pragma unroll
            for (int ms = 0; ms < 2; ++ms) {
                int m = m0 + ms * 16 + la;
                int b = m >> 11, s = m & 2047;
                aO[hf][ms] =
                    ld8(&Ctx[((size_t)(b * NH + hsel) * SEQ + s) * HD + hf * 32 + qd * 8]);
            }
        // async-stage k0+64 into the other buffer
        if (k0 + 64 < DIM) {
            gll16(&Wb[wg0 + k0 + 64], &wst[cur ^ 1][wave * 16][0]);
            gll16(&Wb[wg0 + k0 + 64 + 8 * DIM], &wst[cur ^ 1][wave * 16 + 8][0]);
        }
#pragma unroll
        for (int hf = 0; hf < 2; ++hf)
#pragma unroll
            for (int ns = 0; ns < 4; ++ns) {
                int row = ns * 16 + la;
                int sw = ((hf * 4 + qd) ^ (la & 7)) * 8;
                short8 wv = *(const short8*)&wst[cur][row][sw];
#pragma unroll
                for (int ms = 0; ms < 2; ++ms) acc[ms][ns] = mfma16(aO[hf][ms], wv, acc[ms][ns]);
            }
        __syncthreads();  // release wst[cur]; stage of k0+64 has landed
    }
#pragma unroll
    for (int ns = 0; ns < 4; ++ns) {
        int n = n0 + ns * 16 + la;
        float bvv = bias[n];
#pragma unroll
        for (int ms = 0; ms < 2; ++ms)
#pragma unroll
            for (int r = 0; r < 4; ++r) {
                int m = m0 + ms * 16 + qd * 4 + r;
                __builtin_nontemporal_store(acc[ms][ns][r] + bvv, &out[(size_t)m * DIM + n]);
            }
    }
}

extern "C" void kernel_launch(void* const* d_in, const int* in_sizes, int n_in,
                              void* d_out, int out_size, void* d_ws, size_t ws_size,
                              hipStream_t stream) {
    const float* query = (const float*)d_in[0];
    const float* key   = (const float*)d_in[1];
    const float* value = (const float*)d_in[2];
    const float* Wq = (const float*)d_in[3];
    const float* bq = (const float*)d_in[4];
    const float* Wk = (const float*)d_in[5];
    const float* bk = (const float*)d_in[6];
    const float* Wv = (const float*)d_in[7];
    const float* bv = (const float*)d_in[8];
    const float* Wo = (const float*)d_in[9];
    const float* bo = (const float*)d_in[10];

    float* out  = (float*)d_out;
    float* attn = out + (size_t)MROWS * DIM;

    const size_t NE = (size_t)MROWS * DIM;  // 4,194,304
    const size_t WE = (size_t)DIM * DIM;    // 1,048,576
    ushort* Qhi = (ushort*)d_ws;            // 5 x NE = 40 MiB
    ushort* Qlo = Qhi + NE;
    ushort* Khi = Qlo + NE;
    ushort* Klo = Khi + NE;
    ushort* Vt  = Klo + NE;
    ushort* Wqh = Vt + NE;                  // 6 x WE = 12 MiB
    ushort* Wql = Wqh + WE;
    ushort* Wkh = Wql + WE;
    ushort* Wkl = Wkh + WE;
    ushort* Wvb = Wkl + WE;
    ushort* Wob = Wvb + WE;
    ushort* Ctx = Wqh;                      // overlays Wqh..Wkl (dead after proj_qkv)

    dim3 blk(256);
    hipLaunchKernelGGL(wconv, dim3(WE / 1024, 4), blk, 0, stream,
                       Wq, Wk, Wv, Wo, Wqh, Wql, Wkh, Wkl, Wvb, Wob);
    hipLaunchKernelGGL(proj_qkv, dim3(32, 16, 3), blk, 0, stream,
                       query, key, value, Wqh, Wql, Wkh, Wkl, Wvb, bq, bk, bv,
                       Qhi, Qlo, Khi, Klo, Vt);
    hipLaunchKernelGGL(attn_mfma, dim3(32, 32), blk, 0, stream,
                       Qhi, Qlo, Khi, Klo, Vt, attn, Ctx);
    hipLaunchKernelGGL(proj_out, dim3(32, 16), blk, 0, stream, Ctx, Wob, bo, out);
}

// Round 12
// 875.954 us; speedup vs baseline: 1.0170x; 1.0061x over previous
//
#include <hip/hip_runtime.h>

// SpikingMultiHeadAttention — B=2, S=2048, D=1024, H=16, hd=64, fp32 I/O.
// Round 15: r14 base + ONE change: xconv pre-pass splits query/key into bf16
// hi/lo (and value into bf16) ONCE, memory-bound (~15 µs). proj_qkv's A-path
// becomes pure ld8 (was: fp32 loads + 32 split2/K-step, redone 16x per row
// across grid.y). Same split2/rne16 on same fp32 values -> bit-identical
// MFMA fragments, same accumulation order: absmax must stay 1.75.
// Workspace 52 -> 92 MiB (+5 x NE bf16 X-split buffers).
// Bit algebra (verified at lanes 0/17/35/63):
//   ballot cmp[n2][r]: bit l' = P[(l'>>4)*4+r][n2*16+(l'&15)]
//   pa[j]=P[la][qd*8+j]: bit ((la>>2)*16+(qd&1)*8+j) of cmp[qd>>1][la&3]
//   attn row it*8+(lane>>3), col (lane&7)*4+u:
//     bit ((lane>>5)<<4)+(lane&3)*4 + it*32 + u of cmp[(lane>>2)&1][(lane>>3)&3]
// MFMA 16x16x32 bf16 layouts (HW-verified):
//   A-frag: lane holds A[m=lane&15][k=(lane>>4)*8+j], j=0..7
//   B-frag: lane holds Bt[n=lane&15][k=(lane>>4)*8+j]
//   C/D:    lane,reg r -> row m=(lane>>4)*4+r, col n=lane&15

#define SEQ 2048
#define DIM 1024
#define NH 16
#define HD 64
#define BATCH 2
#define MROWS (BATCH * SEQ)   // 4096
#define BHT (BATCH * NH)      // 32

typedef __attribute__((ext_vector_type(8))) short short8;
typedef __attribute__((ext_vector_type(4))) float f4;
typedef unsigned short ushort;
typedef unsigned long long u64;

__device__ __forceinline__ f4 mfma16(short8 a, short8 b, f4 c) {
    return __builtin_amdgcn_mfma_f32_16x16x32_bf16(a, b, c, 0, 0, 0);
}
__device__ __forceinline__ ushort rne16(float x) {
    union { float f; unsigned u; } a; a.f = x;
    return (ushort)((a.u + 0x7fffu + ((a.u >> 16) & 1u)) >> 16);
}
// x ~= hi + lo: hi = truncate-to-bf16(x), lo = rne-bf16(x - hi)
__device__ __forceinline__ void split2(float x, ushort& h, ushort& l) {
    union { float f; unsigned u; } a; a.f = x;
    unsigned hu = a.u & 0xffff0000u;
    h = (ushort)(hu >> 16);
    union { unsigned u; float f; } hb; hb.u = hu;
    l = rne16(x - hb.f);
}
__device__ __forceinline__ short8 ld8(const ushort* p) { return *(const short8*)p; }

// async global->LDS, 16B per lane; LDS dest wave-uniform base, HW writes
// lane i at base + i*16. Global addr is per-lane.
__device__ __forceinline__ void gll16(const ushort* g, ushort* l) {
    __builtin_amdgcn_global_load_lds((const __attribute__((address_space(1))) void*)g,
                                     (__attribute__((address_space(3))) void*)l, 16, 0, 0);
}

// 4-way select of wave-uniform u64 masks by per-lane index r (0..3)
__device__ __forceinline__ u64 sel4(const u64 c0, const u64 c1, const u64 c2, const u64 c3,
                                    int r) {
    u64 m01 = (r & 1) ? c1 : c0;
    u64 m23 = (r & 1) ? c3 : c2;
    return (r & 2) ? m23 : m01;
}

// ---------- fused weight conversion: 4 jobs on grid.y ----------
__global__ __launch_bounds__(256) void wconv(const float* __restrict__ Wq,
                                             const float* __restrict__ Wk,
                                             const float* __restrict__ Wv,
                                             const float* __restrict__ Wo,
                                             ushort* __restrict__ Wqh, ushort* __restrict__ Wql,
                                             ushort* __restrict__ Wkh, ushort* __restrict__ Wkl,
                                             ushort* __restrict__ Wvb, ushort* __restrict__ Wob) {
    int i = (blockIdx.x * 256 + threadIdx.x) * 4;
    int job = blockIdx.y;
    const float* src = job == 0 ? Wq : job == 1 ? Wk : job == 2 ? Wv : Wo;
    float4 w = *(const float4*)&src[i];
    float xs[4] = {w.x, w.y, w.z, w.w};
    if (job < 2) {
        ushort h[4], l[4];
#pragma unroll
        for (int j = 0; j < 4; ++j) split2(xs[j], h[j], l[j]);
        ushort* ph = job ? Wkh : Wqh;
        ushort* pl = job ? Wkl : Wql;
        *(short4*)&ph[i] = make_short4(h[0], h[1], h[2], h[3]);
        *(short4*)&pl[i] = make_short4(l[0], l[1], l[2], l[3]);
    } else {
        ushort* po = job == 2 ? Wvb : Wob;
        *(short4*)&po[i] = make_short4(rne16(xs[0]), rne16(xs[1]), rne16(xs[2]), rne16(xs[3]));
    }
}

// ---------- input conversion: query/key -> hi/lo bf16, value -> bf16 ----------
// Memory-bound pre-pass; same split2/rne16 as the old inline path ->
// bit-identical fragments downstream.
__global__ __launch_bounds__(256) void xconv(const float* __restrict__ query,
                                             const float* __restrict__ key,
                                             const float* __restrict__ value,
                                             ushort* __restrict__ Xqh, ushort* __restrict__ Xql,
                                             ushort* __restrict__ Xkh, ushort* __restrict__ Xkl,
                                             ushort* __restrict__ Xvb) {
    int i = (blockIdx.x * 256 + threadIdx.x) * 4;
    int job = blockIdx.y;
    const float* src = job == 0 ? query : job == 1 ? key : value;
    float4 w = *(const float4*)&src[i];
    float xs[4] = {w.x, w.y, w.z, w.w};
    if (job < 2) {
        ushort h[4], l[4];
#pragma unroll
        for (int j = 0; j < 4; ++j) split2(xs[j], h[j], l[j]);
        ushort* ph = job ? Xkh : Xqh;
        ushort* pl = job ? Xkl : Xql;
        *(short4*)&ph[i] = make_short4(h[0], h[1], h[2], h[3]);
        *(short4*)&pl[i] = make_short4(l[0], l[1], l[2], l[3]);
    } else {
        *(short4*)&Xvb[i] = make_short4(rne16(xs[0]), rne16(xs[1]), rne16(xs[2]), rne16(xs[3]));
    }
}

// ---------- fused q/k/v projection: W LDS-staged, A pre-split bf16 ----------
// Grid (32, 16, 3). 4 waves/block share the W tile (same n0, different m0).
// LDS: wst[2][2][64][64] = 32 KiB; Ts overlays wst (epilogue-only).
// A-operand now pure ld8 (pre-split by xconv) -> no split2 VALU in hot loop.
__global__ __launch_bounds__(256, 4) void proj_qkv(
    const ushort* __restrict__ Xqh, const ushort* __restrict__ Xql,
    const ushort* __restrict__ Xkh, const ushort* __restrict__ Xkl,
    const ushort* __restrict__ Xvb,
    const ushort* __restrict__ Wqh, const ushort* __restrict__ Wql,
    const ushort* __restrict__ Wkh, const ushort* __restrict__ Wkl,
    const ushort* __restrict__ Wvb,
    const float* __restrict__ bq, const float* __restrict__ bk, const float* __restrict__ bv,
    ushort* __restrict__ Qhi, ushort* __restrict__ Qlo,
    ushort* __restrict__ Khi, ushort* __restrict__ Klo, ushort* __restrict__ Vt) {
    __shared__ ushort wst[2][2][64][64];  // [buf][hi/lo][row][hw], chunk-swizzled content
    // Ts (z==2 epilogue transpose, [4][64][40] = 20 KiB) overlays wst (32 KiB):
    // wst is dead after the K-loop's final __syncthreads.
    ushort (*Ts)[64][40] = (ushort(*)[64][40])(&wst[0][0][0][0]);
    const int z = blockIdx.z;
    const int t = threadIdx.x, wave = t >> 6, lane = t & 63;
    const int la = lane & 15, qd = lane >> 4;
    const int m0 = blockIdx.x * 128 + wave * 32;
    const int n0 = blockIdx.y * 64;

    // staging geometry: wave w stages rows [w*16, w*16+16) of the 64-row W tile
    // in two 8-row gll16 groups. lane l -> row group+(l>>3), chunk (l&7).
    // LDS slot [row][j] holds GLOBAL chunk j^(row&7) (involution); row&7 == l>>3.
    const int srow = wave * 16 + (lane >> 3);
    const int schunk = (lane & 7) ^ (lane >> 3);
    const size_t wg0 = (size_t)(n0 + srow) * DIM + schunk * 8;

    if (z < 2) {
        const ushort* Xh = z ? Xkh : Xqh;
        const ushort* Xl = z ? Xkl : Xql;
        const ushort* Wh = z ? Wkh : Wqh;
        const ushort* Wl = z ? Wkl : Wql;

        // prologue: stage k0=0 into buf 0
        gll16(&Wh[wg0], &wst[0][0][wave * 16][0]);
        gll16(&Wh[wg0 + 8 * DIM], &wst[0][0][wave * 16 + 8][0]);
        gll16(&Wl[wg0], &wst[0][1][wave * 16][0]);
        gll16(&Wl[wg0 + 8 * DIM], &wst[0][1][wave * 16 + 8][0]);
        __syncthreads();

        f4 acc[2][4] = {};
        for (int k0 = 0; k0 < DIM; k0 += 64) {
            const int cur = (k0 >> 6) & 1;
            // A fragments: direct bf16 hi/lo loads (pre-split by xconv)
            short8 aHi[2][2], aLo[2][2];  // [half][ms]
#pragma unroll
            for (int hf = 0; hf < 2; ++hf)
#pragma unroll
                for (int ms = 0; ms < 2; ++ms) {
                    size_t ai = (size_t)(m0 + ms * 16 + la) * DIM + k0 + hf * 32 + qd * 8;
                    aHi[hf][ms] = ld8(&Xh[ai]);
                    aLo[hf][ms] = ld8(&Xl[ai]);
                }
            // async-stage k0+64 into the other buffer
            if (k0 + 64 < DIM) {
                gll16(&Wh[wg0 + k0 + 64], &wst[cur ^ 1][0][wave * 16][0]);
                gll16(&Wh[wg0 + k0 + 64 + 8 * DIM], &wst[cur ^ 1][0][wave * 16 + 8][0]);
                gll16(&Wl[wg0 + k0 + 64], &wst[cur ^ 1][1][wave * 16][0]);
                gll16(&Wl[wg0 + k0 + 64 + 8 * DIM], &wst[cur ^ 1][1][wave * 16 + 8][0]);
            }
#pragma unroll
            for (int hf = 0; hf < 2; ++hf)
#pragma unroll
                for (int ns = 0; ns < 4; ++ns) {
                    int row = ns * 16 + la;
                    int sw = ((hf * 4 + qd) ^ (la & 7)) * 8;
                    short8 wHf = *(const short8*)&wst[cur][0][row][sw];
                    short8 wLf = *(const short8*)&wst[cur][1][row][sw];
#pragma unroll
                    for (int ms = 0; ms < 2; ++ms) {
                        acc[ms][ns] = mfma16(aLo[hf][ms], wHf, acc[ms][ns]);
                        acc[ms][ns] = mfma16(aHi[hf][ms], wLf, acc[ms][ns]);
                        acc[ms][ns] = mfma16(aHi[hf][ms], wHf, acc[ms][ns]);
                    }
                }
            __syncthreads();  // release wst[cur]; stage of k0+64 has landed
        }
        const float* bias = z ? bk : bq;
        ushort* Oh = z ? Khi : Qhi;
        ushort* Ol = z ? Klo : Qlo;
#pragma unroll
        for (int ns = 0; ns < 4; ++ns) {
            int n = n0 + ns * 16 + la;
            float bvv = bias[n];
            int h = n >> 6, d = n & 63;
#pragma unroll
            for (int ms = 0; ms < 2; ++ms)
#pragma unroll
                for (int r = 0; r < 4; ++r) {
                    int m = m0 + ms * 16 + qd * 4 + r;
                    int b = m >> 11, s = m & 2047;
                    ushort hh, ll;
                    split2(acc[ms][ns][r] + bvv, hh, ll);
                    size_t o = ((size_t)(b * NH + h) * SEQ + s) * HD + d;
                    __builtin_nontemporal_store(hh, &Oh[o]);
                    __builtin_nontemporal_store(ll, &Ol[o]);
                }
        }
    } else {
        // V projection: single bf16 W, same staging (hl=0 only); A = Xvb bf16
        gll16(&Wvb[wg0], &wst[0][0][wave * 16][0]);
        gll16(&Wvb[wg0 + 8 * DIM], &wst[0][0][wave * 16 + 8][0]);
        __syncthreads();

        f4 acc[2][4] = {};
        for (int k0 = 0; k0 < DIM; k0 += 64) {
            const int cur = (k0 >> 6) & 1;
            short8 aV[2][2];  // [half][ms]
#pragma unroll
            for (int hf = 0; hf < 2; ++hf)
#pragma unroll
                for (int ms = 0; ms < 2; ++ms) {
                    size_t ai = (size_t)(m0 + ms * 16 + la) * DIM + k0 + hf * 32 + qd * 8;
                    aV[hf][ms] = ld8(&Xvb[ai]);
                }
            if (k0 + 64 < DIM) {
                gll16(&Wvb[wg0 + k0 + 64], &wst[cur ^ 1][0][wave * 16][0]);
                gll16(&Wvb[wg0 + k0 + 64 + 8 * DIM], &wst[cur ^ 1][0][wave * 16 + 8][0]);
            }
#pragma unroll
            for (int hf = 0; hf < 2; ++hf)
#pragma unroll
                for (int ns = 0; ns < 4; ++ns) {
                    int row = ns * 16 + la;
                    int sw = ((hf * 4 + qd) ^ (la & 7)) * 8;
                    short8 wv = *(const short8*)&wst[cur][0][row][sw];
#pragma unroll
                    for (int ms = 0; ms < 2; ++ms) acc[ms][ns] = mfma16(aV[hf][ms], wv, acc[ms][ns]);
                }
            __syncthreads();
        }
        // epilogue: Ts overlays wst — safe, wst dead after the barrier above
#pragma unroll
        for (int ns = 0; ns < 4; ++ns) {
            float bvv = bv[n0 + ns * 16 + la];
#pragma unroll
            for (int ms = 0; ms < 2; ++ms)
#pragma unroll
                for (int r = 0; r < 4; ++r)
                    Ts[wave][ns * 16 + la][ms * 16 + qd * 4 + r] = rne16(acc[ms][ns][r] + bvv);
        }
        // same-wave LDS round-trip (lgkmcnt-ordered, wave-private region)
        int b = m0 >> 11, s0 = m0 & 2047, h = n0 >> 6;
        size_t vbase = (size_t)(b * NH + h) * HD * SEQ;
#pragma unroll
        for (int it = 0; it < 4; ++it) {
            int d = it * 16 + (lane >> 2), sc = (lane & 3) * 8;
            short8 v0 = *(const short8*)&Ts[wave][d][sc];
            __builtin_nontemporal_store(v0, (short8*)&Vt[vbase + (size_t)d * SEQ + s0 + sc]);
        }
    }
}

// ---------- fused attention: LDS-staged K, ballot-based P (no Ps LDS) ----
// Grid 32 (bh) x 32 (q-blocks of 64). 4 waves/block share the K tile.
// LDS: kb[2][2][32][64] = 16 KiB -> 4 blocks/CU (grid-capped).
__global__ __launch_bounds__(256, 4) void attn_mfma(
    const ushort* __restrict__ Qhi, const ushort* __restrict__ Qlo,
    const ushort* __restrict__ Khi, const ushort* __restrict__ Klo,
    const ushort* __restrict__ Vt, float* __restrict__ attn, ushort* __restrict__ ctxb) {
    __shared__ ushort kb[2][2][32][64];  // [buf][hl][key][halfword], chunk-swizzled content
    const int t = threadIdx.x, wave = t >> 6, lane = t & 63;
    const int la = lane & 15, qd = lane >> 4;
    const int bh = blockIdx.x;
    const int q0 = blockIdx.y * 64 + wave * 16;

    short8 qhi[2], qlo[2];
#pragma unroll
    for (int ks = 0; ks < 2; ++ks) {
        size_t qi = ((size_t)bh * SEQ + q0 + la) * HD + ks * 32 + qd * 8;
        qhi[ks] = ld8(&Qhi[qi]);
        qlo[ks] = ld8(&Qlo[qi]);
    }

    const int skey = wave * 8 + (lane >> 3);
    const int schunk = (lane & 7) ^ (lane >> 3);
    const size_t sgbase = ((size_t)bh * SEQ + skey) * HD + schunk * 8;

    // prologue: stage tile 0 into buf 0
    gll16(&Khi[sgbase], &kb[0][0][wave * 8][0]);
    gll16(&Klo[sgbase], &kb[0][1][wave * 8][0]);
    __syncthreads();

    f4 cacc[4] = {};
    for (int h = 0; h < 64; ++h) {
        const int c0 = h * 32;
        const int cur = h & 1;

        short8 vB[4];
#pragma unroll
        for (int ns = 0; ns < 4; ++ns)
            vB[ns] = ld8(&Vt[((size_t)bh * HD + ns * 16 + la) * SEQ + c0 + qd * 8]);

        if (h + 1 < 64) {
            gll16(&Khi[sgbase + (size_t)(c0 + 32) * HD], &kb[cur ^ 1][0][wave * 8][0]);
            gll16(&Klo[sgbase + (size_t)(c0 + 32) * HD], &kb[cur ^ 1][1][wave * 8][0]);
        }

        short8 kH[2][2], kL[2][2];
#pragma unroll
        for (int n2 = 0; n2 < 2; ++n2)
#pragma unroll
            for (int ks = 0; ks < 2; ++ks) {
                int row = n2 * 16 + la;
                int sw = ((ks * 4 + qd) ^ (la & 7)) * 8;
                kH[n2][ks] = *(const short8*)&kb[cur][0][row][sw];
                kL[n2][ks] = *(const short8*)&kb[cur][1][row][sw];
            }

        f4 s[2] = {};
        __builtin_amdgcn_s_setprio(1);
#pragma unroll
        for (int n2 = 0; n2 < 2; ++n2)
#pragma unroll
            for (int ks = 0; ks < 2; ++ks) {
                s[n2] = mfma16(qlo[ks], kH[n2][ks], s[n2]);
                s[n2] = mfma16(qhi[ks], kL[n2][ks], s[n2]);
                s[n2] = mfma16(qhi[ks], kH[n2][ks], s[n2]);
            }
        __builtin_amdgcn_s_setprio(0);

        // P tile as 8 wave-uniform 64-bit masks: bit l' of cmpX[r] =
        // P[(l'>>4)*4+r][n2*16+(l'&15)]
        u64 c00 = __ballot(s[0][0] > 0.f), c01 = __ballot(s[0][1] > 0.f);
        u64 c02 = __ballot(s[0][2] > 0.f), c03 = __ballot(s[0][3] > 0.f);
        u64 c10 = __ballot(s[1][0] > 0.f), c11 = __ballot(s[1][1] > 0.f);
        u64 c12 = __ballot(s[1][2] > 0.f), c13 = __ballot(s[1][3] > 0.f);

        // pa[j] = P[la][qd*8+j] as bf16 0x3f80/0 (bit-identical to old Ps path)
        u64 mq0 = sel4(c00, c01, c02, c03, lane & 3);
        u64 mq1 = sel4(c10, c11, c12, c13, lane & 3);
        u64 mq = (qd & 2) ? mq1 : mq0;
        unsigned pbits = (unsigned)(mq >> ((la >> 2) * 16 + (qd & 1) * 8)) & 0xffu;
        union { unsigned w[4]; short8 s8; } pau;
#pragma unroll
        for (int w = 0; w < 4; ++w)
            pau.w[w] = ((pbits >> (2 * w)) & 1u ? 0x3f80u : 0u) |
                       ((pbits >> (2 * w + 1)) & 1u ? 0x3f800000u : 0u);
        short8 pa = pau.s8;

        // attn tile straight from masks: lane stores rows it*8+(lane>>3),
        // cols c0+(lane&7)*4+u (same addresses as the old Ps-readback path)
        int ra = (lane >> 3) & 3;
        u64 ms0 = sel4(c00, c01, c02, c03, ra);
        u64 ms1 = sel4(c10, c11, c12, c13, ra);
        u64 msel = (lane & 4) ? ms1 : ms0;
        u64 msh = msel >> (((lane >> 5) << 4) + (lane & 3) * 4);
        unsigned blo = (unsigned)msh, bhi = (unsigned)(msh >> 32);
        f4 o0, o1;
        o0.x = (blo & 1u) ? 1.f : 0.f;
        o0.y = (blo & 2u) ? 1.f : 0.f;
        o0.z = (blo & 4u) ? 1.f : 0.f;
        o0.w = (blo & 8u) ? 1.f : 0.f;
        o1.x = (bhi & 1u) ? 1.f : 0.f;
        o1.y = (bhi & 2u) ? 1.f : 0.f;
        o1.z = (bhi & 4u) ? 1.f : 0.f;
        o1.w = (bhi & 8u) ? 1.f : 0.f;
        {
            size_t arow = ((size_t)bh * SEQ + q0 + (lane >> 3)) * SEQ + c0 + (lane & 7) * 4;
            __builtin_nontemporal_store(o0, (f4*)&attn[arow]);
            __builtin_nontemporal_store(o1, (f4*)&attn[arow + (size_t)8 * SEQ]);
        }

        // ctx += P @ V over this 32-key tile
        __builtin_amdgcn_s_setprio(1);
#pragma unroll
        for (int ns = 0; ns < 4; ++ns) cacc[ns] = mfma16(pa, vB[ns], cacc[ns]);
        __builtin_amdgcn_s_setprio(0);

        __syncthreads();
    }
#pragma unroll
    for (int ns = 0; ns < 4; ++ns)
#pragma unroll
        for (int r = 0; r < 4; ++r) {
            int qrow = q0 + qd * 4 + r;
            __builtin_nontemporal_store(rne16(cacc[ns][r]),
                                        &ctxb[((size_t)bh * SEQ + qrow) * HD + ns * 16 + la]);
        }
}

// ---------- out projection: W LDS-staged (dbuf, swizzled) ----------
// Grid (32, 16). 4 waves/block share the W tile (same n0).
// LDS: wst[2][64][64] = 16 KiB -> well within 2 blocks/CU budget.
__global__ __launch_bounds__(256, 2) void proj_out(const ushort* __restrict__ Ctx,
                                                   const ushort* __restrict__ Wb,
                                                   const float* __restrict__ bias,
                                                   float* __restrict__ out) {
    __shared__ ushort wst[2][64][64];  // [buf][row][hw], chunk-swizzled content
    const int t = threadIdx.x, wave = t >> 6, lane = t & 63;
    const int la = lane & 15, qd = lane >> 4;
    const int m0 = blockIdx.x * 128 + wave * 32;
    const int n0 = blockIdx.y * 64;

    const int srow = wave * 16 + (lane >> 3);
    const int schunk = (lane & 7) ^ (lane >> 3);
    const size_t wg0 = (size_t)(n0 + srow) * DIM + schunk * 8;

    // prologue: stage k0=0 into buf 0
    gll16(&Wb[wg0], &wst[0][wave * 16][0]);
    gll16(&Wb[wg0 + 8 * DIM], &wst[0][wave * 16 + 8][0]);
    __syncthreads();

    f4 acc[2][4] = {};
    for (int k0 = 0; k0 < DIM; k0 += 64) {
        const int cur = (k0 >> 6) & 1;
        const int hsel = k0 >> 6;  // head index = k/64 (constant within the tile)
        // Ctx loads (per-wave rows, register path)
        short8 aO[2][2];  // [half][ms]
#pragma unroll
        for (int hf = 0; hf < 2; ++hf)
#pragma unroll
            for (int ms = 0; ms < 2; ++ms) {
                int m = m0 + ms * 16 + la;
                int b = m >> 11, s = m & 2047;
                aO[hf][ms] =
                    ld8(&Ctx[((size_t)(b * NH + hsel) * SEQ + s) * HD + hf * 32 + qd * 8]);
            }
        // async-stage k0+64 into the other buffer
        if (k0 + 64 < DIM) {
            gll16(&Wb[wg0 + k0 + 64], &wst[cur ^ 1][wave * 16][0]);
            gll16(&Wb[wg0 + k0 + 64 + 8 * DIM], &wst[cur ^ 1][wave * 16 + 8][0]);
        }
#pragma unroll
        for (int hf = 0; hf < 2; ++hf)
#pragma unroll
            for (int ns = 0; ns < 4; ++ns) {
                int row = ns * 16 + la;
                int sw = ((hf * 4 + qd) ^ (la & 7)) * 8;
                short8 wv = *(const short8*)&wst[cur][row][sw];
#pragma unroll
                for (int ms = 0; ms < 2; ++ms) acc[ms][ns] = mfma16(aO[hf][ms], wv, acc[ms][ns]);
            }
        __syncthreads();  // release wst[cur]; stage of k0+64 has landed
    }
#pragma unroll
    for (int ns = 0; ns < 4; ++ns) {
        int n = n0 + ns * 16 + la;
        float bvv = bias[n];
#pragma unroll
        for (int ms = 0; ms < 2; ++ms)
#pragma unroll
            for (int r = 0; r < 4; ++r) {
                int m = m0 + ms * 16 + qd * 4 + r;
                __builtin_nontemporal_store(acc[ms][ns][r] + bvv, &out[(size_t)m * DIM + n]);
            }
    }
}

extern "C" void kernel_launch(void* const* d_in, const int* in_sizes, int n_in,
                              void* d_out, int out_size, void* d_ws, size_t ws_size,
                              hipStream_t stream) {
    const float* query = (const float*)d_in[0];
    const float* key   = (const float*)d_in[1];
    const float* value = (const float*)d_in[2];
    const float* Wq = (const float*)d_in[3];
    const float* bq = (const float*)d_in[4];
    const float* Wk = (const float*)d_in[5];
    const float* bk = (const float*)d_in[6];
    const float* Wv = (const float*)d_in[7];
    const float* bv = (const float*)d_in[8];
    const float* Wo = (const float*)d_in[9];
    const float* bo = (const float*)d_in[10];

    float* out  = (float*)d_out;
    float* attn = out + (size_t)MROWS * DIM;

    const size_t NE = (size_t)MROWS * DIM;  // 4,194,304
    const size_t WE = (size_t)DIM * DIM;    // 1,048,576
    ushort* Qhi = (ushort*)d_ws;            // 5 x NE = 40 MiB
    ushort* Qlo = Qhi + NE;
    ushort* Khi = Qlo + NE;
    ushort* Klo = Khi + NE;
    ushort* Vt  = Klo + NE;
    ushort* Wqh = Vt + NE;                  // 6 x WE = 12 MiB
    ushort* Wql = Wqh + WE;
    ushort* Wkh = Wql + WE;
    ushort* Wkl = Wkh + WE;
    ushort* Wvb = Wkl + WE;
    ushort* Wob = Wvb + WE;
    ushort* Xqh = Wob + WE;                 // 5 x NE = 40 MiB (xconv outputs)
    ushort* Xql = Xqh + NE;
    ushort* Xkh = Xql + NE;
    ushort* Xkl = Xkh + NE;
    ushort* Xvb = Xkl + NE;
    ushort* Ctx = Wqh;                      // overlays Wqh..Wkl (dead after proj_qkv)

    dim3 blk(256);
    hipLaunchKernelGGL(wconv, dim3(WE / 1024, 4), blk, 0, stream,
                       Wq, Wk, Wv, Wo, Wqh, Wql, Wkh, Wkl, Wvb, Wob);
    hipLaunchKernelGGL(xconv, dim3(NE / 1024, 3), blk, 0, stream,
                       query, key, value, Xqh, Xql, Xkh, Xkl, Xvb);
    hipLaunchKernelGGL(proj_qkv, dim3(32, 16, 3), blk, 0, stream,
                       Xqh, Xql, Xkh, Xkl, Xvb, Wqh, Wql, Wkh, Wkl, Wvb, bq, bk, bv,
                       Qhi, Qlo, Khi, Klo, Vt);
    hipLaunchKernelGGL(attn_mfma, dim3(32, 32), blk, 0, stream,
                       Qhi, Qlo, Khi, Klo, Vt, attn, Ctx);
    hipLaunchKernelGGL(proj_out, dim3(32, 16), blk, 0, stream, Ctx, Wob, bo, out);
}

// Round 13
// 864.359 us; speedup vs baseline: 1.0306x; 1.0134x over previous
//
#include <hip/hip_runtime.h>

// SpikingMultiHeadAttention — B=2, S=2048, D=1024, H=16, hd=64, fp32 I/O.
// Round 16: r15 base + ONE change: attn_mfma's two f4 attn-tile stores are
// REGULAR stores (NT removed on the 512MB stream only). Theory: NT writes
// cap ~2 TB/s (536MB/264µs observed = 2.0 TB/s; fill kernel = 6.3 TB/s with
// regular stores) and have been the binding constraint since r8 — explaining
// three consecutive neutral rounds (r12/r13/r15). Same values/addresses ->
// absmax must stay 1.75.
// Bit algebra (verified at lanes 0/17/35/63):
//   ballot cmp[n2][r]: bit l' = P[(l'>>4)*4+r][n2*16+(l'&15)]
//   pa[j]=P[la][qd*8+j]: bit ((la>>2)*16+(qd&1)*8+j) of cmp[qd>>1][la&3]
//   attn row it*8+(lane>>3), col (lane&7)*4+u:
//     bit ((lane>>5)<<4)+(lane&3)*4 + it*32 + u of cmp[(lane>>2)&1][(lane>>3)&3]
// MFMA 16x16x32 bf16 layouts (HW-verified):
//   A-frag: lane holds A[m=lane&15][k=(lane>>4)*8+j], j=0..7
//   B-frag: lane holds Bt[n=lane&15][k=(lane>>4)*8+j]
//   C/D:    lane,reg r -> row m=(lane>>4)*4+r, col n=lane&15

#define SEQ 2048
#define DIM 1024
#define NH 16
#define HD 64
#define BATCH 2
#define MROWS (BATCH * SEQ)   // 4096
#define BHT (BATCH * NH)      // 32

typedef __attribute__((ext_vector_type(8))) short short8;
typedef __attribute__((ext_vector_type(4))) float f4;
typedef unsigned short ushort;
typedef unsigned long long u64;

__device__ __forceinline__ f4 mfma16(short8 a, short8 b, f4 c) {
    return __builtin_amdgcn_mfma_f32_16x16x32_bf16(a, b, c, 0, 0, 0);
}
__device__ __forceinline__ ushort rne16(float x) {
    union { float f; unsigned u; } a; a.f = x;
    return (ushort)((a.u + 0x7fffu + ((a.u >> 16) & 1u)) >> 16);
}
// x ~= hi + lo: hi = truncate-to-bf16(x), lo = rne-bf16(x - hi)
__device__ __forceinline__ void split2(float x, ushort& h, ushort& l) {
    union { float f; unsigned u; } a; a.f = x;
    unsigned hu = a.u & 0xffff0000u;
    h = (ushort)(hu >> 16);
    union { unsigned u; float f; } hb; hb.u = hu;
    l = rne16(x - hb.f);
}
__device__ __forceinline__ short8 ld8(const ushort* p) { return *(const short8*)p; }

// async global->LDS, 16B per lane; LDS dest wave-uniform base, HW writes
// lane i at base + i*16. Global addr is per-lane.
__device__ __forceinline__ void gll16(const ushort* g, ushort* l) {
    __builtin_amdgcn_global_load_lds((const __attribute__((address_space(1))) void*)g,
                                     (__attribute__((address_space(3))) void*)l, 16, 0, 0);
}

// 4-way select of wave-uniform u64 masks by per-lane index r (0..3)
__device__ __forceinline__ u64 sel4(const u64 c0, const u64 c1, const u64 c2, const u64 c3,
                                    int r) {
    u64 m01 = (r & 1) ? c1 : c0;
    u64 m23 = (r & 1) ? c3 : c2;
    return (r & 2) ? m23 : m01;
}

// ---------- fused weight conversion: 4 jobs on grid.y ----------
__global__ __launch_bounds__(256) void wconv(const float* __restrict__ Wq,
                                             const float* __restrict__ Wk,
                                             const float* __restrict__ Wv,
                                             const float* __restrict__ Wo,
                                             ushort* __restrict__ Wqh, ushort* __restrict__ Wql,
                                             ushort* __restrict__ Wkh, ushort* __restrict__ Wkl,
                                             ushort* __restrict__ Wvb, ushort* __restrict__ Wob) {
    int i = (blockIdx.x * 256 + threadIdx.x) * 4;
    int job = blockIdx.y;
    const float* src = job == 0 ? Wq : job == 1 ? Wk : job == 2 ? Wv : Wo;
    float4 w = *(const float4*)&src[i];
    float xs[4] = {w.x, w.y, w.z, w.w};
    if (job < 2) {
        ushort h[4], l[4];
#pragma unroll
        for (int j = 0; j < 4; ++j) split2(xs[j], h[j], l[j]);
        ushort* ph = job ? Wkh : Wqh;
        ushort* pl = job ? Wkl : Wql;
        *(short4*)&ph[i] = make_short4(h[0], h[1], h[2], h[3]);
        *(short4*)&pl[i] = make_short4(l[0], l[1], l[2], l[3]);
    } else {
        ushort* po = job == 2 ? Wvb : Wob;
        *(short4*)&po[i] = make_short4(rne16(xs[0]), rne16(xs[1]), rne16(xs[2]), rne16(xs[3]));
    }
}

// ---------- input conversion: query/key -> hi/lo bf16, value -> bf16 ----------
// Memory-bound pre-pass; same split2/rne16 as the old inline path ->
// bit-identical fragments downstream.
__global__ __launch_bounds__(256) void xconv(const float* __restrict__ query,
                                             const float* __restrict__ key,
                                             const float* __restrict__ value,
                                             ushort* __restrict__ Xqh, ushort* __restrict__ Xql,
                                             ushort* __restrict__ Xkh, ushort* __restrict__ Xkl,
                                             ushort* __restrict__ Xvb) {
    int i = (blockIdx.x * 256 + threadIdx.x) * 4;
    int job = blockIdx.y;
    const float* src = job == 0 ? query : job == 1 ? key : value;
    float4 w = *(const float4*)&src[i];
    float xs[4] = {w.x, w.y, w.z, w.w};
    if (job < 2) {
        ushort h[4], l[4];
#pragma unroll
        for (int j = 0; j < 4; ++j) split2(xs[j], h[j], l[j]);
        ushort* ph = job ? Xkh : Xqh;
        ushort* pl = job ? Xkl : Xql;
        *(short4*)&ph[i] = make_short4(h[0], h[1], h[2], h[3]);
        *(short4*)&pl[i] = make_short4(l[0], l[1], l[2], l[3]);
    } else {
        *(short4*)&Xvb[i] = make_short4(rne16(xs[0]), rne16(xs[1]), rne16(xs[2]), rne16(xs[3]));
    }
}

// ---------- fused q/k/v projection: W LDS-staged, A pre-split bf16 ----------
// Grid (32, 16, 3). 4 waves/block share the W tile (same n0, different m0).
// LDS: wst[2][2][64][64] = 32 KiB; Ts overlays wst (epilogue-only).
// A-operand pure ld8 (pre-split by xconv) -> no split2 VALU in hot loop.
__global__ __launch_bounds__(256, 4) void proj_qkv(
    const ushort* __restrict__ Xqh, const ushort* __restrict__ Xql,
    const ushort* __restrict__ Xkh, const ushort* __restrict__ Xkl,
    const ushort* __restrict__ Xvb,
    const ushort* __restrict__ Wqh, const ushort* __restrict__ Wql,
    const ushort* __restrict__ Wkh, const ushort* __restrict__ Wkl,
    const ushort* __restrict__ Wvb,
    const float* __restrict__ bq, const float* __restrict__ bk, const float* __restrict__ bv,
    ushort* __restrict__ Qhi, ushort* __restrict__ Qlo,
    ushort* __restrict__ Khi, ushort* __restrict__ Klo, ushort* __restrict__ Vt) {
    __shared__ ushort wst[2][2][64][64];  // [buf][hi/lo][row][hw], chunk-swizzled content
    // Ts (z==2 epilogue transpose, [4][64][40] = 20 KiB) overlays wst (32 KiB):
    // wst is dead after the K-loop's final __syncthreads.
    ushort (*Ts)[64][40] = (ushort(*)[64][40])(&wst[0][0][0][0]);
    const int z = blockIdx.z;
    const int t = threadIdx.x, wave = t >> 6, lane = t & 63;
    const int la = lane & 15, qd = lane >> 4;
    const int m0 = blockIdx.x * 128 + wave * 32;
    const int n0 = blockIdx.y * 64;

    // staging geometry: wave w stages rows [w*16, w*16+16) of the 64-row W tile
    // in two 8-row gll16 groups. lane l -> row group+(l>>3), chunk (l&7).
    // LDS slot [row][j] holds GLOBAL chunk j^(row&7) (involution); row&7 == l>>3.
    const int srow = wave * 16 + (lane >> 3);
    const int schunk = (lane & 7) ^ (lane >> 3);
    const size_t wg0 = (size_t)(n0 + srow) * DIM + schunk * 8;

    if (z < 2) {
        const ushort* Xh = z ? Xkh : Xqh;
        const ushort* Xl = z ? Xkl : Xql;
        const ushort* Wh = z ? Wkh : Wqh;
        const ushort* Wl = z ? Wkl : Wql;

        // prologue: stage k0=0 into buf 0
        gll16(&Wh[wg0], &wst[0][0][wave * 16][0]);
        gll16(&Wh[wg0 + 8 * DIM], &wst[0][0][wave * 16 + 8][0]);
        gll16(&Wl[wg0], &wst[0][1][wave * 16][0]);
        gll16(&Wl[wg0 + 8 * DIM], &wst[0][1][wave * 16 + 8][0]);
        __syncthreads();

        f4 acc[2][4] = {};
        for (int k0 = 0; k0 < DIM; k0 += 64) {
            const int cur = (k0 >> 6) & 1;
            // A fragments: direct bf16 hi/lo loads (pre-split by xconv)
            short8 aHi[2][2], aLo[2][2];  // [half][ms]
#pragma unroll
            for (int hf = 0; hf < 2; ++hf)
#pragma unroll
                for (int ms = 0; ms < 2; ++ms) {
                    size_t ai = (size_t)(m0 + ms * 16 + la) * DIM + k0 + hf * 32 + qd * 8;
                    aHi[hf][ms] = ld8(&Xh[ai]);
                    aLo[hf][ms] = ld8(&Xl[ai]);
                }
            // async-stage k0+64 into the other buffer
            if (k0 + 64 < DIM) {
                gll16(&Wh[wg0 + k0 + 64], &wst[cur ^ 1][0][wave * 16][0]);
                gll16(&Wh[wg0 + k0 + 64 + 8 * DIM], &wst[cur ^ 1][0][wave * 16 + 8][0]);
                gll16(&Wl[wg0 + k0 + 64], &wst[cur ^ 1][1][wave * 16][0]);
                gll16(&Wl[wg0 + k0 + 64 + 8 * DIM], &wst[cur ^ 1][1][wave * 16 + 8][0]);
            }
#pragma unroll
            for (int hf = 0; hf < 2; ++hf)
#pragma unroll
                for (int ns = 0; ns < 4; ++ns) {
                    int row = ns * 16 + la;
                    int sw = ((hf * 4 + qd) ^ (la & 7)) * 8;
                    short8 wHf = *(const short8*)&wst[cur][0][row][sw];
                    short8 wLf = *(const short8*)&wst[cur][1][row][sw];
#pragma unroll
                    for (int ms = 0; ms < 2; ++ms) {
                        acc[ms][ns] = mfma16(aLo[hf][ms], wHf, acc[ms][ns]);
                        acc[ms][ns] = mfma16(aHi[hf][ms], wLf, acc[ms][ns]);
                        acc[ms][ns] = mfma16(aHi[hf][ms], wHf, acc[ms][ns]);
                    }
                }
            __syncthreads();  // release wst[cur]; stage of k0+64 has landed
        }
        const float* bias = z ? bk : bq;
        ushort* Oh = z ? Khi : Qhi;
        ushort* Ol = z ? Klo : Qlo;
#pragma unroll
        for (int ns = 0; ns < 4; ++ns) {
            int n = n0 + ns * 16 + la;
            float bvv = bias[n];
            int h = n >> 6, d = n & 63;
#pragma unroll
            for (int ms = 0; ms < 2; ++ms)
#pragma unroll
                for (int r = 0; r < 4; ++r) {
                    int m = m0 + ms * 16 + qd * 4 + r;
                    int b = m >> 11, s = m & 2047;
                    ushort hh, ll;
                    split2(acc[ms][ns][r] + bvv, hh, ll);
                    size_t o = ((size_t)(b * NH + h) * SEQ + s) * HD + d;
                    __builtin_nontemporal_store(hh, &Oh[o]);
                    __builtin_nontemporal_store(ll, &Ol[o]);
                }
        }
    } else {
        // V projection: single bf16 W, same staging (hl=0 only); A = Xvb bf16
        gll16(&Wvb[wg0], &wst[0][0][wave * 16][0]);
        gll16(&Wvb[wg0 + 8 * DIM], &wst[0][0][wave * 16 + 8][0]);
        __syncthreads();

        f4 acc[2][4] = {};
        for (int k0 = 0; k0 < DIM; k0 += 64) {
            const int cur = (k0 >> 6) & 1;
            short8 aV[2][2];  // [half][ms]
#pragma unroll
            for (int hf = 0; hf < 2; ++hf)
#pragma unroll
                for (int ms = 0; ms < 2; ++ms) {
                    size_t ai = (size_t)(m0 + ms * 16 + la) * DIM + k0 + hf * 32 + qd * 8;
                    aV[hf][ms] = ld8(&Xvb[ai]);
                }
            if (k0 + 64 < DIM) {
                gll16(&Wvb[wg0 + k0 + 64], &wst[cur ^ 1][0][wave * 16][0]);
                gll16(&Wvb[wg0 + k0 + 64 + 8 * DIM], &wst[cur ^ 1][0][wave * 16 + 8][0]);
            }
#pragma unroll
            for (int hf = 0; hf < 2; ++hf)
#pragma unroll
                for (int ns = 0; ns < 4; ++ns) {
                    int row = ns * 16 + la;
                    int sw = ((hf * 4 + qd) ^ (la & 7)) * 8;
                    short8 wv = *(const short8*)&wst[cur][0][row][sw];
#pragma unroll
                    for (int ms = 0; ms < 2; ++ms) acc[ms][ns] = mfma16(aV[hf][ms], wv, acc[ms][ns]);
                }
            __syncthreads();
        }
        // epilogue: Ts overlays wst — safe, wst dead after the barrier above
#pragma unroll
        for (int ns = 0; ns < 4; ++ns) {
            float bvv = bv[n0 + ns * 16 + la];
#pragma unroll
            for (int ms = 0; ms < 2; ++ms)
#pragma unroll
                for (int r = 0; r < 4; ++r)
                    Ts[wave][ns * 16 + la][ms * 16 + qd * 4 + r] = rne16(acc[ms][ns][r] + bvv);
        }
        // same-wave LDS round-trip (lgkmcnt-ordered, wave-private region)
        int b = m0 >> 11, s0 = m0 & 2047, h = n0 >> 6;
        size_t vbase = (size_t)(b * NH + h) * HD * SEQ;
#pragma unroll
        for (int it = 0; it < 4; ++it) {
            int d = it * 16 + (lane >> 2), sc = (lane & 3) * 8;
            short8 v0 = *(const short8*)&Ts[wave][d][sc];
            __builtin_nontemporal_store(v0, (short8*)&Vt[vbase + (size_t)d * SEQ + s0 + sc]);
        }
    }
}

// ---------- fused attention: LDS-staged K, ballot P, REGULAR attn stores ----
// Grid 32 (bh) x 32 (q-blocks of 64). 4 waves/block share the K tile.
// LDS: kb[2][2][32][64] = 16 KiB -> 4 blocks/CU (grid-capped).
__global__ __launch_bounds__(256, 4) void attn_mfma(
    const ushort* __restrict__ Qhi, const ushort* __restrict__ Qlo,
    const ushort* __restrict__ Khi, const ushort* __restrict__ Klo,
    const ushort* __restrict__ Vt, float* __restrict__ attn, ushort* __restrict__ ctxb) {
    __shared__ ushort kb[2][2][32][64];  // [buf][hl][key][halfword], chunk-swizzled content
    const int t = threadIdx.x, wave = t >> 6, lane = t & 63;
    const int la = lane & 15, qd = lane >> 4;
    const int bh = blockIdx.x;
    const int q0 = blockIdx.y * 64 + wave * 16;

    short8 qhi[2], qlo[2];
#pragma unroll
    for (int ks = 0; ks < 2; ++ks) {
        size_t qi = ((size_t)bh * SEQ + q0 + la) * HD + ks * 32 + qd * 8;
        qhi[ks] = ld8(&Qhi[qi]);
        qlo[ks] = ld8(&Qlo[qi]);
    }

    const int skey = wave * 8 + (lane >> 3);
    const int schunk = (lane & 7) ^ (lane >> 3);
    const size_t sgbase = ((size_t)bh * SEQ + skey) * HD + schunk * 8;

    // prologue: stage tile 0 into buf 0
    gll16(&Khi[sgbase], &kb[0][0][wave * 8][0]);
    gll16(&Klo[sgbase], &kb[0][1][wave * 8][0]);
    __syncthreads();

    f4 cacc[4] = {};
    for (int h = 0; h < 64; ++h) {
        const int c0 = h * 32;
        const int cur = h & 1;

        short8 vB[4];
#pragma unroll
        for (int ns = 0; ns < 4; ++ns)
            vB[ns] = ld8(&Vt[((size_t)bh * HD + ns * 16 + la) * SEQ + c0 + qd * 8]);

        if (h + 1 < 64) {
            gll16(&Khi[sgbase + (size_t)(c0 + 32) * HD], &kb[cur ^ 1][0][wave * 8][0]);
            gll16(&Klo[sgbase + (size_t)(c0 + 32) * HD], &kb[cur ^ 1][1][wave * 8][0]);
        }

        short8 kH[2][2], kL[2][2];
#pragma unroll
        for (int n2 = 0; n2 < 2; ++n2)
#pragma unroll
            for (int ks = 0; ks < 2; ++ks) {
                int row = n2 * 16 + la;
                int sw = ((ks * 4 + qd) ^ (la & 7)) * 8;
                kH[n2][ks] = *(const short8*)&kb[cur][0][row][sw];
                kL[n2][ks] = *(const short8*)&kb[cur][1][row][sw];
            }

        f4 s[2] = {};
        __builtin_amdgcn_s_setprio(1);
#pragma unroll
        for (int n2 = 0; n2 < 2; ++n2)
#pragma unroll
            for (int ks = 0; ks < 2; ++ks) {
                s[n2] = mfma16(qlo[ks], kH[n2][ks], s[n2]);
                s[n2] = mfma16(qhi[ks], kL[n2][ks], s[n2]);
                s[n2] = mfma16(qhi[ks], kH[n2][ks], s[n2]);
            }
        __builtin_amdgcn_s_setprio(0);

        // P tile as 8 wave-uniform 64-bit masks: bit l' of cmpX[r] =
        // P[(l'>>4)*4+r][n2*16+(l'&15)]
        u64 c00 = __ballot(s[0][0] > 0.f), c01 = __ballot(s[0][1] > 0.f);
        u64 c02 = __ballot(s[0][2] > 0.f), c03 = __ballot(s[0][3] > 0.f);
        u64 c10 = __ballot(s[1][0] > 0.f), c11 = __ballot(s[1][1] > 0.f);
        u64 c12 = __ballot(s[1][2] > 0.f), c13 = __ballot(s[1][3] > 0.f);

        // pa[j] = P[la][qd*8+j] as bf16 0x3f80/0 (bit-identical to old Ps path)
        u64 mq0 = sel4(c00, c01, c02, c03, lane & 3);
        u64 mq1 = sel4(c10, c11, c12, c13, lane & 3);
        u64 mq = (qd & 2) ? mq1 : mq0;
        unsigned pbits = (unsigned)(mq >> ((la >> 2) * 16 + (qd & 1) * 8)) & 0xffu;
        union { unsigned w[4]; short8 s8; } pau;
#pragma unroll
        for (int w = 0; w < 4; ++w)
            pau.w[w] = ((pbits >> (2 * w)) & 1u ? 0x3f80u : 0u) |
                       ((pbits >> (2 * w + 1)) & 1u ? 0x3f800000u : 0u);
        short8 pa = pau.s8;

        // attn tile straight from masks: REGULAR stores (L2 write-combining;
        // NT capped ~2 TB/s). Same addresses/values as before.
        int ra = (lane >> 3) & 3;
        u64 ms0 = sel4(c00, c01, c02, c03, ra);
        u64 ms1 = sel4(c10, c11, c12, c13, ra);
        u64 msel = (lane & 4) ? ms1 : ms0;
        u64 msh = msel >> (((lane >> 5) << 4) + (lane & 3) * 4);
        unsigned blo = (unsigned)msh, bhi = (unsigned)(msh >> 32);
        f4 o0, o1;
        o0.x = (blo & 1u) ? 1.f : 0.f;
        o0.y = (blo & 2u) ? 1.f : 0.f;
        o0.z = (blo & 4u) ? 1.f : 0.f;
        o0.w = (blo & 8u) ? 1.f : 0.f;
        o1.x = (bhi & 1u) ? 1.f : 0.f;
        o1.y = (bhi & 2u) ? 1.f : 0.f;
        o1.z = (bhi & 4u) ? 1.f : 0.f;
        o1.w = (bhi & 8u) ? 1.f : 0.f;
        {
            size_t arow = ((size_t)bh * SEQ + q0 + (lane >> 3)) * SEQ + c0 + (lane & 7) * 4;
            *(f4*)&attn[arow] = o0;
            *(f4*)&attn[arow + (size_t)8 * SEQ] = o1;
        }

        // ctx += P @ V over this 32-key tile
        __builtin_amdgcn_s_setprio(1);
#pragma unroll
        for (int ns = 0; ns < 4; ++ns) cacc[ns] = mfma16(pa, vB[ns], cacc[ns]);
        __builtin_amdgcn_s_setprio(0);

        __syncthreads();
    }
#pragma unroll
    for (int ns = 0; ns < 4; ++ns)
#pragma unroll
        for (int r = 0; r < 4; ++r) {
            int qrow = q0 + qd * 4 + r;
            __builtin_nontemporal_store(rne16(cacc[ns][r]),
                                        &ctxb[((size_t)bh * SEQ + qrow) * HD + ns * 16 + la]);
        }
}

// ---------- out projection: W LDS-staged (dbuf, swizzled) ----------
// Grid (32, 16). 4 waves/block share the W tile (same n0).
// LDS: wst[2][64][64] = 16 KiB -> well within 2 blocks/CU budget.
__global__ __launch_bounds__(256, 2) void proj_out(const ushort* __restrict__ Ctx,
                                                   const ushort* __restrict__ Wb,
                                                   const float* __restrict__ bias,
                                                   float* __restrict__ out) {
    __shared__ ushort wst[2][64][64];  // [buf][row][hw], chunk-swizzled content
    const int t = threadIdx.x, wave = t >> 6, lane = t & 63;
    const int la = lane & 15, qd = lane >> 4;
    const int m0 = blockIdx.x * 128 + wave * 32;
    const int n0 = blockIdx.y * 64;

    const int srow = wave * 16 + (lane >> 3);
    const int schunk = (lane & 7) ^ (lane >> 3);
    const size_t wg0 = (size_t)(n0 + srow) * DIM + schunk * 8;

    // prologue: stage k0=0 into buf 0
    gll16(&Wb[wg0], &wst[0][wave * 16][0]);
    gll16(&Wb[wg0 + 8 * DIM], &wst[0][wave * 16 + 8][0]);
    __syncthreads();

    f4 acc[2][4] = {};
    for (int k0 = 0; k0 < DIM; k0 += 64) {
        const int cur = (k0 >> 6) & 1;
        const int hsel = k0 >> 6;  // head index = k/64 (constant within the tile)
        // Ctx loads (per-wave rows, register path)
        short8 aO[2][2];  // [half][ms]
#pragma unroll
        for (int hf = 0; hf < 2; ++hf)
#pragma unroll
            for (int ms = 0; ms < 2; ++ms) {
                int m = m0 + ms * 16 + la;
                int b = m >> 11, s = m & 2047;
                aO[hf][ms] =
                    ld8(&Ctx[((size_t)(b * NH + hsel) * SEQ + s) * HD + hf * 32 + qd * 8]);
            }
        // async-stage k0+64 into the other buffer
        if (k0 + 64 < DIM) {
            gll16(&Wb[wg0 + k0 + 64], &wst[cur ^ 1][wave * 16][0]);
            gll16(&Wb[wg0 + k0 + 64 + 8 * DIM], &wst[cur ^ 1][wave * 16 + 8][0]);
        }
#pragma unroll
        for (int hf = 0; hf < 2; ++hf)
#pragma unroll
            for (int ns = 0; ns < 4; ++ns) {
                int row = ns * 16 + la;
                int sw = ((hf * 4 + qd) ^ (la & 7)) * 8;
                short8 wv = *(const short8*)&wst[cur][row][sw];
#pragma unroll
                for (int ms = 0; ms < 2; ++ms) acc[ms][ns] = mfma16(aO[hf][ms], wv, acc[ms][ns]);
            }
        __syncthreads();  // release wst[cur]; stage of k0+64 has landed
    }
#pragma unroll
    for (int ns = 0; ns < 4; ++ns) {
        int n = n0 + ns * 16 + la;
        float bvv = bias[n];
#pragma unroll
        for (int ms = 0; ms < 2; ++ms)
#pragma unroll
            for (int r = 0; r < 4; ++r) {
                int m = m0 + ms * 16 + qd * 4 + r;
                __builtin_nontemporal_store(acc[ms][ns][r] + bvv, &out[(size_t)m * DIM + n]);
            }
    }
}

extern "C" void kernel_launch(void* const* d_in, const int* in_sizes, int n_in,
                              void* d_out, int out_size, void* d_ws, size_t ws_size,
                              hipStream_t stream) {
    const float* query = (const float*)d_in[0];
    const float* key   = (const float*)d_in[1];
    const float* value = (const float*)d_in[2];
    const float* Wq = (const float*)d_in[3];
    const float* bq = (const float*)d_in[4];
    const float* Wk = (const float*)d_in[5];
    const float* bk = (const float*)d_in[6];
    const float* Wv = (const float*)d_in[7];
    const float* bv = (const float*)d_in[8];
    const float* Wo = (const float*)d_in[9];
    const float* bo = (const float*)d_in[10];

    float* out  = (float*)d_out;
    float* attn = out + (size_t)MROWS * DIM;

    const size_t NE = (size_t)MROWS * DIM;  // 4,194,304
    const size_t WE = (size_t)DIM * DIM;    // 1,048,576
    ushort* Qhi = (ushort*)d_ws;            // 5 x NE = 40 MiB
    ushort* Qlo = Qhi + NE;
    ushort* Khi = Qlo + NE;
    ushort* Klo = Khi + NE;
    ushort* Vt  = Klo + NE;
    ushort* Wqh = Vt + NE;                  // 6 x WE = 12 MiB
    ushort* Wql = Wqh + WE;
    ushort* Wkh = Wql + WE;
    ushort* Wkl = Wkh + WE;
    ushort* Wvb = Wkl + WE;
    ushort* Wob = Wvb + WE;
    ushort* Xqh = Wob + WE;                 // 5 x NE = 40 MiB (xconv outputs)
    ushort* Xql = Xqh + NE;
    ushort* Xkh = Xql + NE;
    ushort* Xkl = Xkh + NE;
    ushort* Xvb = Xkl + NE;
    ushort* Ctx = Wqh;                      // overlays Wqh..Wkl (dead after proj_qkv)

    dim3 blk(256);
    hipLaunchKernelGGL(wconv, dim3(WE / 1024, 4), blk, 0, stream,
                       Wq, Wk, Wv, Wo, Wqh, Wql, Wkh, Wkl, Wvb, Wob);
    hipLaunchKernelGGL(xconv, dim3(NE / 1024, 3), blk, 0, stream,
                       query, key, value, Xqh, Xql, Xkh, Xkl, Xvb);
    hipLaunchKernelGGL(proj_qkv, dim3(32, 16, 3), blk, 0, stream,
                       Xqh, Xql, Xkh, Xkl, Xvb, Wqh, Wql, Wkh, Wkl, Wvb, bq, bk, bv,
                       Qhi, Qlo, Khi, Klo, Vt);
    hipLaunchKernelGGL(attn_mfma, dim3(32, 32), blk, 0, stream,
                       Qhi, Qlo, Khi, Klo, Vt, attn, Ctx);
    hipLaunchKernelGGL(proj_out, dim3(32, 16), blk, 0, stream, Ctx, Wob, bo, out);
}

// Round 14
// 861.446 us; speedup vs baseline: 1.0341x; 1.0034x over previous
//
#include <hip/hip_runtime.h>

// SpikingMultiHeadAttention — B=2, S=2048, D=1024, H=16, hd=64, fp32 I/O.
// Round 17: r16 base + ONE change: attn_mfma uses counted-vmcnt barriers (T4)
// with TRIPLE-buffered K staging. Iteration h computes kb[h%3], stages tile
// h+2 into kb[(h+2)%3]; end-of-iter sync = s_waitcnt vmcnt(4) (this iter's 2
// stage loads + 2 attn stores stay in flight; in-order vmcnt retirement
// guarantees tile h+1's stage, issued a full iteration earlier, has landed)
// + raw s_barrier. __syncthreads' vmcnt(0) drain — the m97-style ~20%
// barrier stall — is gone from the loop. Same loads/MFMA order/store values
// -> absmax must stay 1.75.
// Bit algebra (verified at lanes 0/17/35/63):
//   ballot cmp[n2][r]: bit l' = P[(l'>>4)*4+r][n2*16+(l'&15)]
//   pa[j]=P[la][qd*8+j]: bit ((la>>2)*16+(qd&1)*8+j) of cmp[qd>>1][la&3]
//   attn row it*8+(lane>>3), col (lane&7)*4+u:
//     bit ((lane>>5)<<4)+(lane&3)*4 + it*32 + u of cmp[(lane>>2)&1][(lane>>3)&3]
// MFMA 16x16x32 bf16 layouts (HW-verified):
//   A-frag: lane holds A[m=lane&15][k=(lane>>4)*8+j], j=0..7
//   B-frag: lane holds Bt[n=lane&15][k=(lane>>4)*8+j]
//   C/D:    lane,reg r -> row m=(lane>>4)*4+r, col n=lane&15

#define SEQ 2048
#define DIM 1024
#define NH 16
#define HD 64
#define BATCH 2
#define MROWS (BATCH * SEQ)   // 4096
#define BHT (BATCH * NH)      // 32

typedef __attribute__((ext_vector_type(8))) short short8;
typedef __attribute__((ext_vector_type(4))) float f4;
typedef unsigned short ushort;
typedef unsigned long long u64;

__device__ __forceinline__ f4 mfma16(short8 a, short8 b, f4 c) {
    return __builtin_amdgcn_mfma_f32_16x16x32_bf16(a, b, c, 0, 0, 0);
}
__device__ __forceinline__ ushort rne16(float x) {
    union { float f; unsigned u; } a; a.f = x;
    return (ushort)((a.u + 0x7fffu + ((a.u >> 16) & 1u)) >> 16);
}
// x ~= hi + lo: hi = truncate-to-bf16(x), lo = rne-bf16(x - hi)
__device__ __forceinline__ void split2(float x, ushort& h, ushort& l) {
    union { float f; unsigned u; } a; a.f = x;
    unsigned hu = a.u & 0xffff0000u;
    h = (ushort)(hu >> 16);
    union { unsigned u; float f; } hb; hb.u = hu;
    l = rne16(x - hb.f);
}
__device__ __forceinline__ short8 ld8(const ushort* p) { return *(const short8*)p; }

// async global->LDS, 16B per lane; LDS dest wave-uniform base, HW writes
// lane i at base + i*16. Global addr is per-lane.
__device__ __forceinline__ void gll16(const ushort* g, ushort* l) {
    __builtin_amdgcn_global_load_lds((const __attribute__((address_space(1))) void*)g,
                                     (__attribute__((address_space(3))) void*)l, 16, 0, 0);
}

// 4-way select of wave-uniform u64 masks by per-lane index r (0..3)
__device__ __forceinline__ u64 sel4(const u64 c0, const u64 c1, const u64 c2, const u64 c3,
                                    int r) {
    u64 m01 = (r & 1) ? c1 : c0;
    u64 m23 = (r & 1) ? c3 : c2;
    return (r & 2) ? m23 : m01;
}

// ---------- fused weight conversion: 4 jobs on grid.y ----------
__global__ __launch_bounds__(256) void wconv(const float* __restrict__ Wq,
                                             const float* __restrict__ Wk,
                                             const float* __restrict__ Wv,
                                             const float* __restrict__ Wo,
                                             ushort* __restrict__ Wqh, ushort* __restrict__ Wql,
                                             ushort* __restrict__ Wkh, ushort* __restrict__ Wkl,
                                             ushort* __restrict__ Wvb, ushort* __restrict__ Wob) {
    int i = (blockIdx.x * 256 + threadIdx.x) * 4;
    int job = blockIdx.y;
    const float* src = job == 0 ? Wq : job == 1 ? Wk : job == 2 ? Wv : Wo;
    float4 w = *(const float4*)&src[i];
    float xs[4] = {w.x, w.y, w.z, w.w};
    if (job < 2) {
        ushort h[4], l[4];
#pragma unroll
        for (int j = 0; j < 4; ++j) split2(xs[j], h[j], l[j]);
        ushort* ph = job ? Wkh : Wqh;
        ushort* pl = job ? Wkl : Wql;
        *(short4*)&ph[i] = make_short4(h[0], h[1], h[2], h[3]);
        *(short4*)&pl[i] = make_short4(l[0], l[1], l[2], l[3]);
    } else {
        ushort* po = job == 2 ? Wvb : Wob;
        *(short4*)&po[i] = make_short4(rne16(xs[0]), rne16(xs[1]), rne16(xs[2]), rne16(xs[3]));
    }
}

// ---------- input conversion: query/key -> hi/lo bf16, value -> bf16 ----------
// Memory-bound pre-pass; same split2/rne16 as the old inline path ->
// bit-identical fragments downstream.
__global__ __launch_bounds__(256) void xconv(const float* __restrict__ query,
                                             const float* __restrict__ key,
                                             const float* __restrict__ value,
                                             ushort* __restrict__ Xqh, ushort* __restrict__ Xql,
                                             ushort* __restrict__ Xkh, ushort* __restrict__ Xkl,
                                             ushort* __restrict__ Xvb) {
    int i = (blockIdx.x * 256 + threadIdx.x) * 4;
    int job = blockIdx.y;
    const float* src = job == 0 ? query : job == 1 ? key : value;
    float4 w = *(const float4*)&src[i];
    float xs[4] = {w.x, w.y, w.z, w.w};
    if (job < 2) {
        ushort h[4], l[4];
#pragma unroll
        for (int j = 0; j < 4; ++j) split2(xs[j], h[j], l[j]);
        ushort* ph = job ? Xkh : Xqh;
        ushort* pl = job ? Xkl : Xql;
        *(short4*)&ph[i] = make_short4(h[0], h[1], h[2], h[3]);
        *(short4*)&pl[i] = make_short4(l[0], l[1], l[2], l[3]);
    } else {
        *(short4*)&Xvb[i] = make_short4(rne16(xs[0]), rne16(xs[1]), rne16(xs[2]), rne16(xs[3]));
    }
}

// ---------- fused q/k/v projection: W LDS-staged, A pre-split bf16 ----------
// Grid (32, 16, 3). 4 waves/block share the W tile (same n0, different m0).
// LDS: wst[2][2][64][64] = 32 KiB; Ts overlays wst (epilogue-only).
// A-operand pure ld8 (pre-split by xconv) -> no split2 VALU in hot loop.
__global__ __launch_bounds__(256, 4) void proj_qkv(
    const ushort* __restrict__ Xqh, const ushort* __restrict__ Xql,
    const ushort* __restrict__ Xkh, const ushort* __restrict__ Xkl,
    const ushort* __restrict__ Xvb,
    const ushort* __restrict__ Wqh, const ushort* __restrict__ Wql,
    const ushort* __restrict__ Wkh, const ushort* __restrict__ Wkl,
    const ushort* __restrict__ Wvb,
    const float* __restrict__ bq, const float* __restrict__ bk, const float* __restrict__ bv,
    ushort* __restrict__ Qhi, ushort* __restrict__ Qlo,
    ushort* __restrict__ Khi, ushort* __restrict__ Klo, ushort* __restrict__ Vt) {
    __shared__ ushort wst[2][2][64][64];  // [buf][hi/lo][row][hw], chunk-swizzled content
    // Ts (z==2 epilogue transpose, [4][64][40] = 20 KiB) overlays wst (32 KiB):
    // wst is dead after the K-loop's final __syncthreads.
    ushort (*Ts)[64][40] = (ushort(*)[64][40])(&wst[0][0][0][0]);
    const int z = blockIdx.z;
    const int t = threadIdx.x, wave = t >> 6, lane = t & 63;
    const int la = lane & 15, qd = lane >> 4;
    const int m0 = blockIdx.x * 128 + wave * 32;
    const int n0 = blockIdx.y * 64;

    // staging geometry: wave w stages rows [w*16, w*16+16) of the 64-row W tile
    // in two 8-row gll16 groups. lane l -> row group+(l>>3), chunk (l&7).
    // LDS slot [row][j] holds GLOBAL chunk j^(row&7) (involution); row&7 == l>>3.
    const int srow = wave * 16 + (lane >> 3);
    const int schunk = (lane & 7) ^ (lane >> 3);
    const size_t wg0 = (size_t)(n0 + srow) * DIM + schunk * 8;

    if (z < 2) {
        const ushort* Xh = z ? Xkh : Xqh;
        const ushort* Xl = z ? Xkl : Xql;
        const ushort* Wh = z ? Wkh : Wqh;
        const ushort* Wl = z ? Wkl : Wql;

        // prologue: stage k0=0 into buf 0
        gll16(&Wh[wg0], &wst[0][0][wave * 16][0]);
        gll16(&Wh[wg0 + 8 * DIM], &wst[0][0][wave * 16 + 8][0]);
        gll16(&Wl[wg0], &wst[0][1][wave * 16][0]);
        gll16(&Wl[wg0 + 8 * DIM], &wst[0][1][wave * 16 + 8][0]);
        __syncthreads();

        f4 acc[2][4] = {};
        for (int k0 = 0; k0 < DIM; k0 += 64) {
            const int cur = (k0 >> 6) & 1;
            // A fragments: direct bf16 hi/lo loads (pre-split by xconv)
            short8 aHi[2][2], aLo[2][2];  // [half][ms]
#pragma unroll
            for (int hf = 0; hf < 2; ++hf)
#pragma unroll
                for (int ms = 0; ms < 2; ++ms) {
                    size_t ai = (size_t)(m0 + ms * 16 + la) * DIM + k0 + hf * 32 + qd * 8;
                    aHi[hf][ms] = ld8(&Xh[ai]);
                    aLo[hf][ms] = ld8(&Xl[ai]);
                }
            // async-stage k0+64 into the other buffer
            if (k0 + 64 < DIM) {
                gll16(&Wh[wg0 + k0 + 64], &wst[cur ^ 1][0][wave * 16][0]);
                gll16(&Wh[wg0 + k0 + 64 + 8 * DIM], &wst[cur ^ 1][0][wave * 16 + 8][0]);
                gll16(&Wl[wg0 + k0 + 64], &wst[cur ^ 1][1][wave * 16][0]);
                gll16(&Wl[wg0 + k0 + 64 + 8 * DIM], &wst[cur ^ 1][1][wave * 16 + 8][0]);
            }
#pragma unroll
            for (int hf = 0; hf < 2; ++hf)
#pragma unroll
                for (int ns = 0; ns < 4; ++ns) {
                    int row = ns * 16 + la;
                    int sw = ((hf * 4 + qd) ^ (la & 7)) * 8;
                    short8 wHf = *(const short8*)&wst[cur][0][row][sw];
                    short8 wLf = *(const short8*)&wst[cur][1][row][sw];
#pragma unroll
                    for (int ms = 0; ms < 2; ++ms) {
                        acc[ms][ns] = mfma16(aLo[hf][ms], wHf, acc[ms][ns]);
                        acc[ms][ns] = mfma16(aHi[hf][ms], wLf, acc[ms][ns]);
                        acc[ms][ns] = mfma16(aHi[hf][ms], wHf, acc[ms][ns]);
                    }
                }
            __syncthreads();  // release wst[cur]; stage of k0+64 has landed
        }
        const float* bias = z ? bk : bq;
        ushort* Oh = z ? Khi : Qhi;
        ushort* Ol = z ? Klo : Qlo;
#pragma unroll
        for (int ns = 0; ns < 4; ++ns) {
            int n = n0 + ns * 16 + la;
            float bvv = bias[n];
            int h = n >> 6, d = n & 63;
#pragma unroll
            for (int ms = 0; ms < 2; ++ms)
#pragma unroll
                for (int r = 0; r < 4; ++r) {
                    int m = m0 + ms * 16 + qd * 4 + r;
                    int b = m >> 11, s = m & 2047;
                    ushort hh, ll;
                    split2(acc[ms][ns][r] + bvv, hh, ll);
                    size_t o = ((size_t)(b * NH + h) * SEQ + s) * HD + d;
                    __builtin_nontemporal_store(hh, &Oh[o]);
                    __builtin_nontemporal_store(ll, &Ol[o]);
                }
        }
    } else {
        // V projection: single bf16 W, same staging (hl=0 only); A = Xvb bf16
        gll16(&Wvb[wg0], &wst[0][0][wave * 16][0]);
        gll16(&Wvb[wg0 + 8 * DIM], &wst[0][0][wave * 16 + 8][0]);
        __syncthreads();

        f4 acc[2][4] = {};
        for (int k0 = 0; k0 < DIM; k0 += 64) {
            const int cur = (k0 >> 6) & 1;
            short8 aV[2][2];  // [half][ms]
#pragma unroll
            for (int hf = 0; hf < 2; ++hf)
#pragma unroll
                for (int ms = 0; ms < 2; ++ms) {
                    size_t ai = (size_t)(m0 + ms * 16 + la) * DIM + k0 + hf * 32 + qd * 8;
                    aV[hf][ms] = ld8(&Xvb[ai]);
                }
            if (k0 + 64 < DIM) {
                gll16(&Wvb[wg0 + k0 + 64], &wst[cur ^ 1][0][wave * 16][0]);
                gll16(&Wvb[wg0 + k0 + 64 + 8 * DIM], &wst[cur ^ 1][0][wave * 16 + 8][0]);
            }
#pragma unroll
            for (int hf = 0; hf < 2; ++hf)
#pragma unroll
                for (int ns = 0; ns < 4; ++ns) {
                    int row = ns * 16 + la;
                    int sw = ((hf * 4 + qd) ^ (la & 7)) * 8;
                    short8 wv = *(const short8*)&wst[cur][0][row][sw];
#pragma unroll
                    for (int ms = 0; ms < 2; ++ms) acc[ms][ns] = mfma16(aV[hf][ms], wv, acc[ms][ns]);
                }
            __syncthreads();
        }
        // epilogue: Ts overlays wst — safe, wst dead after the barrier above
#pragma unroll
        for (int ns = 0; ns < 4; ++ns) {
            float bvv = bv[n0 + ns * 16 + la];
#pragma unroll
            for (int ms = 0; ms < 2; ++ms)
#pragma unroll
                for (int r = 0; r < 4; ++r)
                    Ts[wave][ns * 16 + la][ms * 16 + qd * 4 + r] = rne16(acc[ms][ns][r] + bvv);
        }
        // same-wave LDS round-trip (lgkmcnt-ordered, wave-private region)
        int b = m0 >> 11, s0 = m0 & 2047, h = n0 >> 6;
        size_t vbase = (size_t)(b * NH + h) * HD * SEQ;
#pragma unroll
        for (int it = 0; it < 4; ++it) {
            int d = it * 16 + (lane >> 2), sc = (lane & 3) * 8;
            short8 v0 = *(const short8*)&Ts[wave][d][sc];
            __builtin_nontemporal_store(v0, (short8*)&Vt[vbase + (size_t)d * SEQ + s0 + sc]);
        }
    }
}

// ---------- fused attention: triple-buffered K, counted-vmcnt barriers ----
// Grid 32 (bh) x 32 (q-blocks of 64). 4 waves/block share the K tile.
// LDS: kb[3][2][32][64] = 24 KiB -> 4 blocks/CU (grid-capped).
// Iteration h: compute kb[h%3], stage tile h+2 into kb[(h+2)%3].
// End-of-iter: s_waitcnt vmcnt(4) (2 stages + 2 stores of THIS iter allowed
// outstanding; in-order retirement drains tile h+1's stage) + s_barrier.
__global__ __launch_bounds__(256, 4) void attn_mfma(
    const ushort* __restrict__ Qhi, const ushort* __restrict__ Qlo,
    const ushort* __restrict__ Khi, const ushort* __restrict__ Klo,
    const ushort* __restrict__ Vt, float* __restrict__ attn, ushort* __restrict__ ctxb) {
    __shared__ ushort kb[3][2][32][64];  // [buf][hl][key][halfword], chunk-swizzled content
    const int t = threadIdx.x, wave = t >> 6, lane = t & 63;
    const int la = lane & 15, qd = lane >> 4;
    const int bh = blockIdx.x;
    const int q0 = blockIdx.y * 64 + wave * 16;

    short8 qhi[2], qlo[2];
#pragma unroll
    for (int ks = 0; ks < 2; ++ks) {
        size_t qi = ((size_t)bh * SEQ + q0 + la) * HD + ks * 32 + qd * 8;
        qhi[ks] = ld8(&Qhi[qi]);
        qlo[ks] = ld8(&Qlo[qi]);
    }

    const int skey = wave * 8 + (lane >> 3);
    const int schunk = (lane & 7) ^ (lane >> 3);
    const size_t sgbase = ((size_t)bh * SEQ + skey) * HD + schunk * 8;

    // prologue: stage tiles 0 and 1; wait for tile 0 only (allow tile 1's 2
    // loads outstanding), then barrier.
    gll16(&Khi[sgbase], &kb[0][0][wave * 8][0]);
    gll16(&Klo[sgbase], &kb[0][1][wave * 8][0]);
    gll16(&Khi[sgbase + (size_t)32 * HD], &kb[1][0][wave * 8][0]);
    gll16(&Klo[sgbase + (size_t)32 * HD], &kb[1][1][wave * 8][0]);
    asm volatile("s_waitcnt vmcnt(2)" ::: "memory");
    __builtin_amdgcn_s_barrier();

    f4 cacc[4] = {};
    for (int h = 0; h < 64; ++h) {
        const int c0 = h * 32;
        const int cur = h % 3;

        short8 vB[4];
#pragma unroll
        for (int ns = 0; ns < 4; ++ns)
            vB[ns] = ld8(&Vt[((size_t)bh * HD + ns * 16 + la) * SEQ + c0 + qd * 8]);

        // stage tile h+2 two iterations ahead (read at h+2; its landing is
        // guaranteed by the vmcnt(4) at the END of iteration h+1).
        const bool staged = (h + 2 < 64);
        if (staged) {
            const size_t sn = sgbase + (size_t)(c0 + 64) * HD;
            gll16(&Khi[sn], &kb[(h + 2) % 3][0][wave * 8][0]);
            gll16(&Klo[sn], &kb[(h + 2) % 3][1][wave * 8][0]);
        }

        short8 kH[2][2], kL[2][2];
#pragma unroll
        for (int n2 = 0; n2 < 2; ++n2)
#pragma unroll
            for (int ks = 0; ks < 2; ++ks) {
                int row = n2 * 16 + la;
                int sw = ((ks * 4 + qd) ^ (la & 7)) * 8;
                kH[n2][ks] = *(const short8*)&kb[cur][0][row][sw];
                kL[n2][ks] = *(const short8*)&kb[cur][1][row][sw];
            }

        f4 s[2] = {};
        __builtin_amdgcn_s_setprio(1);
#pragma unroll
        for (int n2 = 0; n2 < 2; ++n2)
#pragma unroll
            for (int ks = 0; ks < 2; ++ks) {
                s[n2] = mfma16(qlo[ks], kH[n2][ks], s[n2]);
                s[n2] = mfma16(qhi[ks], kL[n2][ks], s[n2]);
                s[n2] = mfma16(qhi[ks], kH[n2][ks], s[n2]);
            }
        __builtin_amdgcn_s_setprio(0);

        // P tile as 8 wave-uniform 64-bit masks
        u64 c00 = __ballot(s[0][0] > 0.f), c01 = __ballot(s[0][1] > 0.f);
        u64 c02 = __ballot(s[0][2] > 0.f), c03 = __ballot(s[0][3] > 0.f);
        u64 c10 = __ballot(s[1][0] > 0.f), c11 = __ballot(s[1][1] > 0.f);
        u64 c12 = __ballot(s[1][2] > 0.f), c13 = __ballot(s[1][3] > 0.f);

        // pa[j] = P[la][qd*8+j] as bf16 0x3f80/0
        u64 mq0 = sel4(c00, c01, c02, c03, lane & 3);
        u64 mq1 = sel4(c10, c11, c12, c13, lane & 3);
        u64 mq = (qd & 2) ? mq1 : mq0;
        unsigned pbits = (unsigned)(mq >> ((la >> 2) * 16 + (qd & 1) * 8)) & 0xffu;
        union { unsigned w[4]; short8 s8; } pau;
#pragma unroll
        for (int w = 0; w < 4; ++w)
            pau.w[w] = ((pbits >> (2 * w)) & 1u ? 0x3f80u : 0u) |
                       ((pbits >> (2 * w + 1)) & 1u ? 0x3f800000u : 0u);
        short8 pa = pau.s8;

        // attn tile straight from masks (regular stores, r16)
        int ra = (lane >> 3) & 3;
        u64 ms0 = sel4(c00, c01, c02, c03, ra);
        u64 ms1 = sel4(c10, c11, c12, c13, ra);
        u64 msel = (lane & 4) ? ms1 : ms0;
        u64 msh = msel >> (((lane >> 5) << 4) + (lane & 3) * 4);
        unsigned blo = (unsigned)msh, bhi = (unsigned)(msh >> 32);
        f4 o0, o1;
        o0.x = (blo & 1u) ? 1.f : 0.f;
        o0.y = (blo & 2u) ? 1.f : 0.f;
        o0.z = (blo & 4u) ? 1.f : 0.f;
        o0.w = (blo & 8u) ? 1.f : 0.f;
        o1.x = (bhi & 1u) ? 1.f : 0.f;
        o1.y = (bhi & 2u) ? 1.f : 0.f;
        o1.z = (bhi & 4u) ? 1.f : 0.f;
        o1.w = (bhi & 8u) ? 1.f : 0.f;
        {
            size_t arow = ((size_t)bh * SEQ + q0 + (lane >> 3)) * SEQ + c0 + (lane & 7) * 4;
            *(f4*)&attn[arow] = o0;
            *(f4*)&attn[arow + (size_t)8 * SEQ] = o1;
        }

        // ctx += P @ V over this 32-key tile
        __builtin_amdgcn_s_setprio(1);
#pragma unroll
        for (int ns = 0; ns < 4; ++ns) cacc[ns] = mfma16(pa, vB[ns], cacc[ns]);
        __builtin_amdgcn_s_setprio(0);

        // counted-vmcnt barrier: allow this iter's in-flight VMEM (2 stage
        // loads + 2 stores when staged; 2 stores only at h=62); everything
        // older — incl. tile h+1's stage — is drained by in-order retirement.
        if (h < 63) {
            if (staged) {
                asm volatile("s_waitcnt vmcnt(4)" ::: "memory");
            } else {
                asm volatile("s_waitcnt vmcnt(2)" ::: "memory");
            }
            __builtin_amdgcn_s_barrier();
        }
    }
#pragma unroll
    for (int ns = 0; ns < 4; ++ns)
#pragma unroll
        for (int r = 0; r < 4; ++r) {
            int qrow = q0 + qd * 4 + r;
            __builtin_nontemporal_store(rne16(cacc[ns][r]),
                                        &ctxb[((size_t)bh * SEQ + qrow) * HD + ns * 16 + la]);
        }
}

// ---------- out projection: W LDS-staged (dbuf, swizzled) ----------
// Grid (32, 16). 4 waves/block share the W tile (same n0).
// LDS: wst[2][64][64] = 16 KiB -> well within 2 blocks/CU budget.
__global__ __launch_bounds__(256, 2) void proj_out(const ushort* __restrict__ Ctx,
                                                   const ushort* __restrict__ Wb,
                                                   const float* __restrict__ bias,
                                                   float* __restrict__ out) {
    __shared__ ushort wst[2][64][64];  // [buf][row][hw], chunk-swizzled content
    const int t = threadIdx.x, wave = t >> 6, lane = t & 63;
    const int la = lane & 15, qd = lane >> 4;
    const int m0 = blockIdx.x * 128 + wave * 32;
    const int n0 = blockIdx.y * 64;

    const int srow = wave * 16 + (lane >> 3);
    const int schunk = (lane & 7) ^ (lane >> 3);
    const size_t wg0 = (size_t)(n0 + srow) * DIM + schunk * 8;

    // prologue: stage k0=0 into buf 0
    gll16(&Wb[wg0], &wst[0][wave * 16][0]);
    gll16(&Wb[wg0 + 8 * DIM], &wst[0][wave * 16 + 8][0]);
    __syncthreads();

    f4 acc[2][4] = {};
    for (int k0 = 0; k0 < DIM; k0 += 64) {
        const int cur = (k0 >> 6) & 1;
        const int hsel = k0 >> 6;  // head index = k/64 (constant within the tile)
        // Ctx loads (per-wave rows, register path)
        short8 aO[2][2];  // [half][ms]
#pragma unroll
        for (int hf = 0; hf < 2; ++hf)
#pragma unroll
            for (int ms = 0; ms < 2; ++ms) {
                int m = m0 + ms * 16 + la;
                int b = m >> 11, s = m & 2047;
                aO[hf][ms] =
                    ld8(&Ctx[((size_t)(b * NH + hsel) * SEQ + s) * HD + hf * 32 + qd * 8]);
            }
        // async-stage k0+64 into the other buffer
        if (k0 + 64 < DIM) {
            gll16(&Wb[wg0 + k0 + 64], &wst[cur ^ 1][wave * 16][0]);
            gll16(&Wb[wg0 + k0 + 64 + 8 * DIM], &wst[cur ^ 1][wave * 16 + 8][0]);
        }
#pragma unroll
        for (int hf = 0; hf < 2; ++hf)
#pragma unroll
            for (int ns = 0; ns < 4; ++ns) {
                int row = ns * 16 + la;
                int sw = ((hf * 4 + qd) ^ (la & 7)) * 8;
                short8 wv = *(const short8*)&wst[cur][row][sw];
#pragma unroll
                for (int ms = 0; ms < 2; ++ms) acc[ms][ns] = mfma16(aO[hf][ms], wv, acc[ms][ns]);
            }
        __syncthreads();  // release wst[cur]; stage of k0+64 has landed
    }
#pragma unroll
    for (int ns = 0; ns < 4; ++ns) {
        int n = n0 + ns * 16 + la;
        float bvv = bias[n];
#pragma unroll
        for (int ms = 0; ms < 2; ++ms)
#pragma unroll
            for (int r = 0; r < 4; ++r) {
                int m = m0 + ms * 16 + qd * 4 + r;
                __builtin_nontemporal_store(acc[ms][ns][r] + bvv, &out[(size_t)m * DIM + n]);
            }
    }
}

extern "C" void kernel_launch(void* const* d_in, const int* in_sizes, int n_in,
                              void* d_out, int out_size, void* d_ws, size_t ws_size,
                              hipStream_t stream) {
    const float* query = (const float*)d_in[0];
    const float* key   = (const float*)d_in[1];
    const float* value = (const float*)d_in[2];
    const float* Wq = (const float*)d_in[3];
    const float* bq = (const float*)d_in[4];
    const float* Wk = (const float*)d_in[5];
    const float* bk = (const float*)d_in[6];
    const float* Wv = (const float*)d_in[7];
    const float* bv = (const float*)d_in[8];
    const float* Wo = (const float*)d_in[9];
    const float* bo = (const float*)d_in[10];

    float* out  = (float*)d_out;
    float* attn = out + (size_t)MROWS * DIM;

    const size_t NE = (size_t)MROWS * DIM;  // 4,194,304
    const size_t WE = (size_t)DIM * DIM;    // 1,048,576
    ushort* Qhi = (ushort*)d_ws;            // 5 x NE = 40 MiB
    ushort* Qlo = Qhi + NE;
    ushort* Khi = Qlo + NE;
    ushort* Klo = Khi + NE;
    ushort* Vt  = Klo + NE;
    ushort* Wqh = Vt + NE;                  // 6 x WE = 12 MiB
    ushort* Wql = Wqh + WE;
    ushort* Wkh = Wql + WE;
    ushort* Wkl = Wkh + WE;
    ushort* Wvb = Wkl + WE;
    ushort* Wob = Wvb + WE;
    ushort* Xqh = Wob + WE;                 // 5 x NE = 40 MiB (xconv outputs)
    ushort* Xql = Xqh + NE;
    ushort* Xkh = Xql + NE;
    ushort* Xkl = Xkh + NE;
    ushort* Xvb = Xkl + NE;
    ushort* Ctx = Wqh;                      // overlays Wqh..Wkl (dead after proj_qkv)

    dim3 blk(256);
    hipLaunchKernelGGL(wconv, dim3(WE / 1024, 4), blk, 0, stream,
                       Wq, Wk, Wv, Wo, Wqh, Wql, Wkh, Wkl, Wvb, Wob);
    hipLaunchKernelGGL(xconv, dim3(NE / 1024, 3), blk, 0, stream,
                       query, key, value, Xqh, Xql, Xkh, Xkl, Xvb);
    hipLaunchKernelGGL(proj_qkv, dim3(32, 16, 3), blk, 0, stream,
                       Xqh, Xql, Xkh, Xkl, Xvb, Wqh, Wql, Wkh, Wkl, Wvb, bq, bk, bv,
                       Qhi, Qlo, Khi, Klo, Vt);
    hipLaunchKernelGGL(attn_mfma, dim3(32, 32), blk, 0, stream,
                       Qhi, Qlo, Khi, Klo, Vt, attn, Ctx);
    hipLaunchKernelGGL(proj_out, dim3(32, 16), blk, 0, stream, Ctx, Wob, bo, out);
}